// Round 9
// baseline (456.055 us; speedup 1.0000x reference)
//
#include <hip/hip_runtime.h>
#include <math.h>

#define NN 100000
#define NE 1600000
#define EPS_BN 1e-5f
#define EPS_NORM 1e-12f
#define SLOPE 0.01f
#define STATS_BLOCKS 1024
#define STATS_THREADS 512
#define SCAN_BLOCKS ((NN + 255) / 256)       // 391
#define GS_LEN (64 * SCAN_BLOCKS)            // 25024
#define GS_BLOCKS ((GS_LEN + 255) / 256)     // 98

__device__ __forceinline__ float fast_tanh(float x) {
    // tanh(x) = 1 - 2/(exp2(x*2*log2e)+1); exact saturation at +-inf
    float t = exp2f(x * 2.885390082f);
    return fmaf(-2.0f, __builtin_amdgcn_rcpf(t + 1.0f), 1.0f);
}

// Pass 0: in-degree histogram (int4-vectorized edge-dst read).
__global__ void __launch_bounds__(256) deg_kernel(
    const int* __restrict__ ei, int* __restrict__ deg)
{
    int t = blockIdx.x * 256 + threadIdx.x;
    if (t * 4 >= NE) return;
    int4 d4 = *(const int4*)(ei + NE + t * 4);
    atomicAdd(&deg[d4.x], 1);
    atomicAdd(&deg[d4.y], 1);
    atomicAdd(&deg[d4.z], 1);
    atomicAdd(&deg[d4.w], 1);
}

// Pass 1a: per-block exclusive scan of deg -> rowptr (block-local) + block sums.
__global__ void __launch_bounds__(256) scanA_kernel(
    const int* __restrict__ deg, int* __restrict__ rowptr, int* __restrict__ bsum)
{
    int b = blockIdx.x, t = threadIdx.x;
    int i = b * 256 + t;
    int d = (i < NN) ? deg[i] : 0;
    __shared__ int sh[256];
    sh[t] = d;
    __syncthreads();
    for (int off = 1; off < 256; off <<= 1) {
        int val = (t >= off) ? sh[t - off] : 0;
        __syncthreads();
        sh[t] += val;
        __syncthreads();
    }
    if (i < NN) rowptr[i] = sh[t] - d;     // exclusive within block
    if (t == 255) bsum[b] = sh[255];
}

// Pass 1b: add block offsets in-place; also emit cursor copy.
__global__ void __launch_bounds__(256) scanC_kernel(
    int* __restrict__ rowptr, const int* __restrict__ bsum, int* __restrict__ cursor)
{
    int b = blockIdx.x, t = threadIdx.x;
    __shared__ int sh[256];
    int s = 0;
    for (int j = t; j < b; j += 256) s += bsum[j];
    sh[t] = s;
    __syncthreads();
    for (int off = 128; off > 0; off >>= 1) {
        if (t < off) sh[t] += sh[t + off];
        __syncthreads();
    }
    int boff = sh[0];
    int i = b * 256 + t;
    if (i < NN) {
        int r = rowptr[i] + boff;
        rowptr[i] = r;
        cursor[i] = r;
    }
    if (b == 0 && t == 0) rowptr[NN] = NE;
}

// Pass 2: FUSED scatter + e-moment stats (wide grid for atomic latency hiding).
__global__ void __launch_bounds__(STATS_THREADS) scatstat_kernel(
    const float* __restrict__ v,
    const int* __restrict__ ei,
    const float* __restrict__ ea,
    int* __restrict__ cursor,
    unsigned long long* __restrict__ recs,   // packed {lo=src, hi=bf16x2 attr}
    float* __restrict__ partials)   // [STATS_BLOCKS][77]
{
    float acc[77];
#pragma unroll
    for (int i = 0; i < 77; ++i) acc[i] = 0.0f;

    int tid = blockIdx.x * STATS_THREADS + threadIdx.x;
    int stride = STATS_BLOCKS * STATS_THREADS;
    for (int eidx = tid; eidx < NE; eidx += stride) {
        int s = ei[eidx];
        int d = ei[NE + eidx];
        float2 a2 = *(const float2*)(ea + 2 * (size_t)eidx);

        float4 s0 = *(const float4*)(v + (size_t)s * 8);
        float4 s1 = *(const float4*)(v + (size_t)s * 8 + 4);
        float4 d0 = *(const float4*)(v + (size_t)d * 8);
        float4 d1 = *(const float4*)(v + (size_t)d * 8 + 4);
        float df[8];
        df[0] = d0.x - s0.x; df[1] = d0.y - s0.y;
        df[2] = d0.z - s0.z; df[3] = d0.w - s0.w;
        df[4] = d1.x - s1.x; df[5] = d1.y - s1.y;
        df[6] = d1.z - s1.z; df[7] = d1.w - s1.w;
        float nsq = 0.0f;
#pragma unroll
        for (int i = 0; i < 8; ++i) nsq = fmaf(df[i], df[i], nsq);
        float nrm = sqrtf(nsq);
        float inv = __builtin_amdgcn_rcpf(nrm + EPS_NORM);
        float e[11];
        e[0] = a2.x; e[1] = a2.y; e[2] = nrm;
#pragma unroll
        for (int i = 0; i < 8; ++i) e[3 + i] = df[i] * inv;

        int p = 11;
#pragma unroll
        for (int k = 0; k < 11; ++k) {
            acc[k] += e[k];
#pragma unroll
            for (int l = k; l < 11; ++l) { acc[p] = fmaf(e[k], e[l], acc[p]); ++p; }
        }

        unsigned ua = __float_as_uint(a2.x), ub = __float_as_uint(a2.y);
        unsigned pa = (ua + 0x7fffu + ((ua >> 16) & 1u)) >> 16;   // rne bf16
        unsigned pb = (ub + 0x7fffu + ((ub >> 16) & 1u)) >> 16;
        unsigned hi = (pa << 16) | pb;
        unsigned long long rec = ((unsigned long long)hi << 32) | (unsigned)s;
        int idx = atomicAdd(&cursor[d], 1);
        __builtin_nontemporal_store(rec, &recs[idx]);
    }

#pragma unroll
    for (int i = 0; i < 77; ++i) {
        float x = acc[i];
        for (int off = 32; off > 0; off >>= 1) x += __shfl_down(x, off);
        acc[i] = x;
    }
    __shared__ float lsum[8][77];
    int wave = threadIdx.x >> 6;
    int lane = threadIdx.x & 63;
    if (lane == 0) {
#pragma unroll
        for (int i = 0; i < 77; ++i) lsum[wave][i] = acc[i];
    }
    __syncthreads();
    if (threadIdx.x < 77) {
        float t = 0.0f;
#pragma unroll
        for (int w = 0; w < 8; ++w) t += lsum[w][threadIdx.x];
        partials[blockIdx.x * 77 + threadIdx.x] = t;
    }
}

// Pass 3: reduce partials, closed-form BN, fold scale into W' and b'.
__global__ void bn_finalize_kernel(
    const float* __restrict__ partials,
    const float* __restrict__ w0, const float* __restrict__ b0,
    const float* __restrict__ g0, const float* __restrict__ be0,
    const float* __restrict__ w1, const float* __restrict__ b1,
    const float* __restrict__ g1, const float* __restrict__ be1,
    float* __restrict__ wbp)   // layer l at +l*768: W'[704] then b'[64]
{
    __shared__ double gs[77];
    int t = threadIdx.x;
    if (t < 77) {
        double s = 0.0;
        for (int b = 0; b < STATS_BLOCKS; b += 4) {
            s += (double)partials[b * 77 + t] + (double)partials[(b + 1) * 77 + t]
               + (double)partials[(b + 2) * 77 + t] + (double)partials[(b + 3) * 77 + t];
        }
        gs[t] = s;
    }
    __syncthreads();
    if (t >= 128) return;
    int layer = t >> 6;
    int c = t & 63;
    const float* W  = layer ? w1 : w0;
    const float* B  = layer ? b1 : b0;
    const float* G  = layer ? g1 : g0;
    const float* BE = layer ? be1 : be0;

    const double invE = 1.0 / (double)NE;
    double m[11], wv[11];
    for (int k = 0; k < 11; ++k) {
        m[k] = gs[k] * invE;
        wv[k] = (double)W[k * 64 + c];
    }
    double md = 0.0;
    for (int k = 0; k < 11; ++k) md += m[k] * wv[k];
    double s2 = 0.0;
    int p = 11;
    for (int k = 0; k < 11; ++k)
        for (int l = k; l < 11; ++l) {
            double Me = gs[p] * invE; ++p;
            double term = Me * wv[k] * wv[l];
            s2 += (k == l) ? term : 2.0 * term;
        }
    double var = s2 - md * md;
    double mu = md + (double)B[c];
    float scale = (float)((double)G[c] / sqrt(var + (double)EPS_BN));
    float shift = (float)((double)BE[c] - mu * (double)scale);

    float* wpd = wbp + layer * 768;
    for (int k = 0; k < 11; ++k) wpd[k * 64 + c] = W[k * 64 + c] * scale;
    wpd[704 + c] = fmaf(B[c], scale, shift);
}

// Degree-bucket counting sort (DESCENDING: heavy nodes first -> LPT schedule).
__global__ void __launch_bounds__(256) bucketA_kernel(
    const int* __restrict__ rowptr, int* __restrict__ pr, int* __restrict__ bhT)
{
    __shared__ int lh[64];
    int t = threadIdx.x, b = blockIdx.x;
    if (t < 64) lh[t] = 0;
    __syncthreads();
    int n = b * 256 + t;
    if (n < NN) {
        int d = rowptr[n + 1] - rowptr[n];
        int db = d < 63 ? d : 63;
        int bkt = 63 - db;                      // descending degree order
        int lrank = atomicAdd(&lh[bkt], 1);     // LDS atomic: block-local only
        pr[n] = (lrank << 6) | bkt;
    }
    __syncthreads();
    if (t < 64) bhT[t * SCAN_BLOCKS + b] = lh[t];   // bucket-major layout
}

// Generic exclusive scan over bhT (bucket-major => scan yields global offsets).
__global__ void __launch_bounds__(256) gscanA_kernel(
    int* __restrict__ a, int* __restrict__ gbsum)
{
    int b = blockIdx.x, t = threadIdx.x;
    int i = b * 256 + t;
    int d = (i < GS_LEN) ? a[i] : 0;
    __shared__ int sh[256];
    sh[t] = d;
    __syncthreads();
    for (int off = 1; off < 256; off <<= 1) {
        int val = (t >= off) ? sh[t - off] : 0;
        __syncthreads();
        sh[t] += val;
        __syncthreads();
    }
    if (i < GS_LEN) a[i] = sh[t] - d;
    if (t == 255) gbsum[b] = sh[255];
}

__global__ void __launch_bounds__(256) gscanB_kernel(
    int* __restrict__ a, const int* __restrict__ gbsum)
{
    int b = blockIdx.x, t = threadIdx.x;
    __shared__ int sh[256];
    int s = 0;
    for (int j = t; j < b; j += 256) s += gbsum[j];
    sh[t] = s;
    __syncthreads();
    for (int off = 128; off > 0; off >>= 1) {
        if (t < off) sh[t] += sh[t + off];
        __syncthreads();
    }
    int boff = sh[0];
    int i = b * 256 + t;
    if (i < GS_LEN) a[i] += boff;
}

// Emit int4 perm records {node, rowptr[n], rowptr[n+1], 0}.
__global__ void __launch_bounds__(256) permB_kernel(
    const int* __restrict__ pr, const int* __restrict__ bhT,
    const int* __restrict__ rowptr, int4* __restrict__ perm4)
{
    int n = blockIdx.x * 256 + threadIdx.x;
    if (n >= NN) return;
    int p = pr[n];
    int bkt = p & 63, lrank = p >> 6, b = n >> 8;
    int pos = bhT[bkt * SCAN_BLOCKS + b] + lrank;
    perm4[pos] = make_int4(n, rowptr[n], rowptr[n + 1], 0);
}

// One edge's worth of MLP+message work (weights/vd/msg live in caller regs).
#define EDGE_BODY(RR, XI, SA, SB)                                            \
    do {                                                                     \
        unsigned p_ = (unsigned)((RR) >> 32);                                \
        float e_[11];                                                        \
        e_[0] = __uint_as_float(p_ & 0xffff0000u);                           \
        e_[1] = __uint_as_float(p_ << 16);                                   \
        float df_[8];                                                        \
        df_[0] = vd[0] - (SA).x; df_[1] = vd[1] - (SA).y;                    \
        df_[2] = vd[2] - (SA).z; df_[3] = vd[3] - (SA).w;                    \
        df_[4] = vd[4] - (SB).x; df_[5] = vd[5] - (SB).y;                    \
        df_[6] = vd[6] - (SB).z; df_[7] = vd[7] - (SB).w;                    \
        float nsq_ = 0.0f;                                                   \
        _Pragma("unroll")                                                    \
        for (int q = 0; q < 8; ++q) nsq_ = fmaf(df_[q], df_[q], nsq_);       \
        float nrm_ = sqrtf(nsq_);                                            \
        float invn_ = __builtin_amdgcn_rcpf(nrm_ + EPS_NORM);                \
        e_[2] = nrm_;                                                        \
        _Pragma("unroll")                                                    \
        for (int q = 0; q < 8; ++q) e_[3 + q] = df_[q] * invn_;              \
        _Pragma("unroll")                                                    \
        for (int o = 0; o < 8; ++o) {                                        \
            float hh_ = breg[o];                                             \
            _Pragma("unroll")                                                \
            for (int k = 0; k < 11; ++k) hh_ = fmaf(e_[k], wreg[k][o], hh_); \
            msg[o] = fmaf((XI), fast_tanh(hh_), msg[o]);                     \
        }                                                                    \
    } while (0)

// Pass 5 (per layer): fused gather-message + mean + root + lrelu (+residual).
// 8 threads per dst node (degree-sorted desc); weights in registers;
// 2-edge unrolled pipeline for memory-level parallelism.
template<int LAYER>
__global__ void __launch_bounds__(256) layer_kernel(
    const float* __restrict__ vres,
    const float* __restrict__ x,       // v for L0, v1 for L1
    const unsigned long long* __restrict__ recs,
    const int4* __restrict__ perm4,
    const float* __restrict__ wb,      // [768] W' then b'
    const float* __restrict__ rw, const float* __restrict__ rb,
    float* __restrict__ out)
{
    int g = blockIdx.x * 256 + threadIdx.x;   // g < 8*NN exactly
    int4 pm = perm4[g >> 3];
    int n = pm.x, rp0 = pm.y, rp1 = pm.z;
    int i = g & 7;

    float wreg[11][8];
#pragma unroll
    for (int k = 0; k < 11; ++k) {
        float4 wa = *(const float4*)(wb + k * 64 + i * 8);
        float4 wc = *(const float4*)(wb + k * 64 + i * 8 + 4);
        wreg[k][0] = wa.x; wreg[k][1] = wa.y; wreg[k][2] = wa.z; wreg[k][3] = wa.w;
        wreg[k][4] = wc.x; wreg[k][5] = wc.y; wreg[k][6] = wc.z; wreg[k][7] = wc.w;
    }
    float breg[8];
    {
        float4 ba = *(const float4*)(wb + 704 + i * 8);
        float4 bb = *(const float4*)(wb + 704 + i * 8 + 4);
        breg[0] = ba.x; breg[1] = ba.y; breg[2] = ba.z; breg[3] = ba.w;
        breg[4] = bb.x; breg[5] = bb.y; breg[6] = bb.z; breg[7] = bb.w;
    }

    float4 vd0 = *(const float4*)(vres + (size_t)n * 8);
    float4 vd1 = *(const float4*)(vres + (size_t)n * 8 + 4);
    float vd[8] = {vd0.x, vd0.y, vd0.z, vd0.w, vd1.x, vd1.y, vd1.z, vd1.w};

    float msg[8];
#pragma unroll
    for (int o = 0; o < 8; ++o) msg[o] = 0.0f;

    int j = rp0;
    for (; j + 2 <= rp1; j += 2) {
        unsigned long long r0 = recs[j];
        unsigned long long r1 = recs[j + 1];
        int s0i = (int)(unsigned)r0;
        int s1i = (int)(unsigned)r1;
        float xi0 = x[(size_t)s0i * 8 + i];
        float xi1 = x[(size_t)s1i * 8 + i];
        float4 s00 = *(const float4*)(vres + (size_t)s0i * 8);
        float4 s01 = *(const float4*)(vres + (size_t)s0i * 8 + 4);
        float4 s10 = *(const float4*)(vres + (size_t)s1i * 8);
        float4 s11 = *(const float4*)(vres + (size_t)s1i * 8 + 4);
        EDGE_BODY(r0, xi0, s00, s01);
        EDGE_BODY(r1, xi1, s10, s11);
    }
    if (j < rp1) {
        unsigned long long r0 = recs[j];
        int s0i = (int)(unsigned)r0;
        float xi0 = x[(size_t)s0i * 8 + i];
        float4 s00 = *(const float4*)(vres + (size_t)s0i * 8);
        float4 s01 = *(const float4*)(vres + (size_t)s0i * 8 + 4);
        EDGE_BODY(r0, xi0, s00, s01);
    }

    // sum partial msg over the 8 lanes of this node-group
#pragma unroll
    for (int o = 0; o < 8; ++o) {
        float m = msg[o];
        m += __shfl_xor(m, 1);
        m += __shfl_xor(m, 2);
        m += __shfl_xor(m, 4);
        msg[o] = m;
    }
    float mo = msg[0];
#pragma unroll
    for (int o = 1; o < 8; ++o) if (i == o) mo = msg[o];

    float cf = (float)(rp1 - rp0);
    float invc = __builtin_amdgcn_rcpf(fmaxf(cf, 1.0f));

    float xn[8];
    if (LAYER == 0) {
#pragma unroll
        for (int q = 0; q < 8; ++q) xn[q] = vd[q];
    } else {
        float4 x0 = *(const float4*)(x + (size_t)n * 8);
        float4 x1 = *(const float4*)(x + (size_t)n * 8 + 4);
        xn[0] = x0.x; xn[1] = x0.y; xn[2] = x0.z; xn[3] = x0.w;
        xn[4] = x1.x; xn[5] = x1.y; xn[6] = x1.z; xn[7] = x1.w;
    }
    float a = fmaf(mo, invc, rb[i]);
#pragma unroll
    for (int k = 0; k < 8; ++k) a = fmaf(xn[k], rw[k * 8 + i], a);
    float y = (a > 0.0f) ? a : SLOPE * a;
    if (LAYER == 1) y += vres[(size_t)n * 8 + i];
    out[(size_t)n * 8 + i] = y;
}

extern "C" void kernel_launch(void* const* d_in, const int* in_sizes, int n_in,
                              void* d_out, int out_size, void* d_ws, size_t ws_size,
                              hipStream_t stream) {
    const float* v  = (const float*)d_in[0];
    const int* ei   = (const int*)d_in[1];
    const float* ea = (const float*)d_in[2];
    const float* en_w0  = (const float*)d_in[3];
    const float* en_b0  = (const float*)d_in[4];
    const float* en_g0  = (const float*)d_in[5];
    const float* en_be0 = (const float*)d_in[6];
    const float* rw0    = (const float*)d_in[7];
    const float* rb0    = (const float*)d_in[8];
    const float* en_w1  = (const float*)d_in[9];
    const float* en_b1  = (const float*)d_in[10];
    const float* en_g1  = (const float*)d_in[11];
    const float* en_be1 = (const float*)d_in[12];
    const float* rw1    = (const float*)d_in[13];
    const float* rb1    = (const float*)d_in[14];

    char* ws = (char*)d_ws;
    float* partials = (float*)(ws);                   // 1024*77*4 = 315,392 B
    float* wbp      = (float*)(ws + 327680);          // 6,144 B
    int*   deg      = (int*)  (ws + 335872);          // 400,000 B
    int*   rowptr   = (int*)  (ws + 737280);          // 400,004 B
    int*   bsum     = (int*)  (ws + 1138688);         // 1,564 B
    int*   pr       = (int*)  (ws + 1142784);         // 400,000 B
    int4*  perm4    = (int4*) (ws + 1544192);         // 1,600,000 B
    int*   cursor   = (int*)  (ws + 3145728);         // 400,000 B
    int*   bhT      = (int*)  (ws + 3547136);         // 100,096 B
    int*   gbsum    = (int*)  (ws + 3647488);         // 392 B
    float* v1       = (float*)(ws + 3649536);         // 3,200,000 B
    unsigned long long* recs = (unsigned long long*)(ws + 6850560); // 12,800,000 B
    float* vout     = (float*)d_out;

    hipMemsetAsync(deg, 0, NN * sizeof(int), stream);

    deg_kernel<<<(NE / 4 + 255) / 256, 256, 0, stream>>>(ei, deg);
    scanA_kernel<<<SCAN_BLOCKS, 256, 0, stream>>>(deg, rowptr, bsum);
    scanC_kernel<<<SCAN_BLOCKS, 256, 0, stream>>>(rowptr, bsum, cursor);
    scatstat_kernel<<<STATS_BLOCKS, STATS_THREADS, 0, stream>>>(v, ei, ea, cursor, recs, partials);
    bn_finalize_kernel<<<1, 128, 0, stream>>>(partials, en_w0, en_b0, en_g0, en_be0,
                                              en_w1, en_b1, en_g1, en_be1, wbp);
    bucketA_kernel<<<SCAN_BLOCKS, 256, 0, stream>>>(rowptr, pr, bhT);
    gscanA_kernel<<<GS_BLOCKS, 256, 0, stream>>>(bhT, gbsum);
    gscanB_kernel<<<GS_BLOCKS, 256, 0, stream>>>(bhT, gbsum);
    permB_kernel<<<SCAN_BLOCKS, 256, 0, stream>>>(pr, bhT, rowptr, perm4);

    const int LB = (NN * 8) / 256;   // 3125, exact
    layer_kernel<0><<<LB, 256, 0, stream>>>(v, v,  recs, perm4, wbp,       rw0, rb0, v1);
    layer_kernel<1><<<LB, 256, 0, stream>>>(v, v1, recs, perm4, wbp + 768, rw1, rb1, vout);
}

// Round 10
// 438.852 us; speedup vs baseline: 1.0392x; 1.0392x over previous
//
#include <hip/hip_runtime.h>
#include <hip/hip_fp16.h>
#include <math.h>

#define NN 100000
#define NE 1600000
#define EPS_BN 1e-5f
#define EPS_NORM 1e-12f
#define SLOPE 0.01f
#define STATS_BLOCKS 1024
#define STATS_THREADS 512
#define SCAN_BLOCKS ((NN + 255) / 256)       // 391
#define GS_LEN (64 * SCAN_BLOCKS)            // 25024
#define GS_BLOCKS ((GS_LEN + 255) / 256)     // 98
#define FAT_WS_NEEDED 58050560ULL

__device__ __forceinline__ float fast_tanh(float x) {
    // tanh(x) = 1 - 2/(exp2(x*2*log2e)+1); exact saturation at +-inf
    float t = exp2f(x * 2.885390082f);
    return fmaf(-2.0f, __builtin_amdgcn_rcpf(t + 1.0f), 1.0f);
}

__device__ __forceinline__ unsigned pk2(float a, float b) {
    union { __half2 h; unsigned u; } c;
    c.h = __float22half2_rn(make_float2(a, b));
    return c.u;
}
__device__ __forceinline__ float2 upk2(unsigned u) {
    union { unsigned u; __half2 h; } c; c.u = u;
    return __half22float2(c.h);
}

// Pass 0: in-degree histogram (int4-vectorized edge-dst read).
__global__ void __launch_bounds__(256) deg_kernel(
    const int* __restrict__ ei, int* __restrict__ deg)
{
    int t = blockIdx.x * 256 + threadIdx.x;
    if (t * 4 >= NE) return;
    int4 d4 = *(const int4*)(ei + NE + t * 4);
    atomicAdd(&deg[d4.x], 1);
    atomicAdd(&deg[d4.y], 1);
    atomicAdd(&deg[d4.z], 1);
    atomicAdd(&deg[d4.w], 1);
}

// Pass 1a: per-block exclusive scan of deg -> rowptr (block-local) + block sums.
__global__ void __launch_bounds__(256) scanA_kernel(
    const int* __restrict__ deg, int* __restrict__ rowptr, int* __restrict__ bsum)
{
    int b = blockIdx.x, t = threadIdx.x;
    int i = b * 256 + t;
    int d = (i < NN) ? deg[i] : 0;
    __shared__ int sh[256];
    sh[t] = d;
    __syncthreads();
    for (int off = 1; off < 256; off <<= 1) {
        int val = (t >= off) ? sh[t - off] : 0;
        __syncthreads();
        sh[t] += val;
        __syncthreads();
    }
    if (i < NN) rowptr[i] = sh[t] - d;     // exclusive within block
    if (t == 255) bsum[b] = sh[255];
}

// Pass 1b: add block offsets in-place; also emit cursor copy.
__global__ void __launch_bounds__(256) scanC_kernel(
    int* __restrict__ rowptr, const int* __restrict__ bsum, int* __restrict__ cursor)
{
    int b = blockIdx.x, t = threadIdx.x;
    __shared__ int sh[256];
    int s = 0;
    for (int j = t; j < b; j += 256) s += bsum[j];
    sh[t] = s;
    __syncthreads();
    for (int off = 128; off > 0; off >>= 1) {
        if (t < off) sh[t] += sh[t + off];
        __syncthreads();
    }
    int boff = sh[0];
    int i = b * 256 + t;
    if (i < NN) {
        int r = rowptr[i] + boff;
        rowptr[i] = r;
        cursor[i] = r;
    }
    if (b == 0 && t == 0) rowptr[NN] = NE;
}

// Pass 2: FUSED scatter + e-moment stats. FAT: rec = 32B {fp16 e[11], src}.
// THIN: rec = 8B {src, bf16x2 attr}.
template<bool FAT>
__global__ void __launch_bounds__(STATS_THREADS) scatstat_kernel(
    const float* __restrict__ v,
    const int* __restrict__ ei,
    const float* __restrict__ ea,
    int* __restrict__ cursor,
    unsigned long long* __restrict__ recs,
    uint4* __restrict__ recsF,
    float* __restrict__ partials)   // [STATS_BLOCKS][77]
{
    float acc[77];
#pragma unroll
    for (int i = 0; i < 77; ++i) acc[i] = 0.0f;

    int tid = blockIdx.x * STATS_THREADS + threadIdx.x;
    int stride = STATS_BLOCKS * STATS_THREADS;
    for (int eidx = tid; eidx < NE; eidx += stride) {
        int s = ei[eidx];
        int d = ei[NE + eidx];
        float2 a2 = *(const float2*)(ea + 2 * (size_t)eidx);

        float4 s0 = *(const float4*)(v + (size_t)s * 8);
        float4 s1 = *(const float4*)(v + (size_t)s * 8 + 4);
        float4 d0 = *(const float4*)(v + (size_t)d * 8);
        float4 d1 = *(const float4*)(v + (size_t)d * 8 + 4);
        float df[8];
        df[0] = d0.x - s0.x; df[1] = d0.y - s0.y;
        df[2] = d0.z - s0.z; df[3] = d0.w - s0.w;
        df[4] = d1.x - s1.x; df[5] = d1.y - s1.y;
        df[6] = d1.z - s1.z; df[7] = d1.w - s1.w;
        float nsq = 0.0f;
#pragma unroll
        for (int i = 0; i < 8; ++i) nsq = fmaf(df[i], df[i], nsq);
        float nrm = sqrtf(nsq);
        float inv = __builtin_amdgcn_rcpf(nrm + EPS_NORM);
        float e[11];
        e[0] = a2.x; e[1] = a2.y; e[2] = nrm;
#pragma unroll
        for (int i = 0; i < 8; ++i) e[3 + i] = df[i] * inv;

        int p = 11;
#pragma unroll
        for (int k = 0; k < 11; ++k) {
            acc[k] += e[k];
#pragma unroll
            for (int l = k; l < 11; ++l) { acc[p] = fmaf(e[k], e[l], acc[p]); ++p; }
        }

        int idx = atomicAdd(&cursor[d], 1);
        if (FAT) {
            uint4 lo, hi;
            lo.x = pk2(e[0], e[1]); lo.y = pk2(e[2], e[3]);
            lo.z = pk2(e[4], e[5]); lo.w = pk2(e[6], e[7]);
            hi.x = pk2(e[8], e[9]); hi.y = pk2(e[10], 0.0f);
            hi.z = (unsigned)s;     hi.w = 0u;
            recsF[(size_t)idx * 2]     = lo;
            recsF[(size_t)idx * 2 + 1] = hi;
        } else {
            unsigned ua = __float_as_uint(a2.x), ub = __float_as_uint(a2.y);
            unsigned pa = (ua + 0x7fffu + ((ua >> 16) & 1u)) >> 16;   // rne bf16
            unsigned pb = (ub + 0x7fffu + ((ub >> 16) & 1u)) >> 16;
            unsigned hi = (pa << 16) | pb;
            recs[idx] = ((unsigned long long)hi << 32) | (unsigned)s;
        }
    }

#pragma unroll
    for (int i = 0; i < 77; ++i) {
        float x = acc[i];
        for (int off = 32; off > 0; off >>= 1) x += __shfl_down(x, off);
        acc[i] = x;
    }
    __shared__ float lsum[8][77];
    int wave = threadIdx.x >> 6;
    int lane = threadIdx.x & 63;
    if (lane == 0) {
#pragma unroll
        for (int i = 0; i < 77; ++i) lsum[wave][i] = acc[i];
    }
    __syncthreads();
    if (threadIdx.x < 77) {
        float t = 0.0f;
#pragma unroll
        for (int w = 0; w < 8; ++w) t += lsum[w][threadIdx.x];
        partials[blockIdx.x * 77 + threadIdx.x] = t;
    }
}

// Pass 3: reduce partials, closed-form BN, fold scale into W' and b'.
__global__ void bn_finalize_kernel(
    const float* __restrict__ partials,
    const float* __restrict__ w0, const float* __restrict__ b0,
    const float* __restrict__ g0, const float* __restrict__ be0,
    const float* __restrict__ w1, const float* __restrict__ b1,
    const float* __restrict__ g1, const float* __restrict__ be1,
    float* __restrict__ wbp)   // layer l at +l*768: W'[704] then b'[64]
{
    __shared__ double gs[77];
    int t = threadIdx.x;
    if (t < 77) {
        double s = 0.0;
        for (int b = 0; b < STATS_BLOCKS; b += 4) {
            s += (double)partials[b * 77 + t] + (double)partials[(b + 1) * 77 + t]
               + (double)partials[(b + 2) * 77 + t] + (double)partials[(b + 3) * 77 + t];
        }
        gs[t] = s;
    }
    __syncthreads();
    if (t >= 128) return;
    int layer = t >> 6;
    int c = t & 63;
    const float* W  = layer ? w1 : w0;
    const float* B  = layer ? b1 : b0;
    const float* G  = layer ? g1 : g0;
    const float* BE = layer ? be1 : be0;

    const double invE = 1.0 / (double)NE;
    double m[11], wv[11];
    for (int k = 0; k < 11; ++k) {
        m[k] = gs[k] * invE;
        wv[k] = (double)W[k * 64 + c];
    }
    double md = 0.0;
    for (int k = 0; k < 11; ++k) md += m[k] * wv[k];
    double s2 = 0.0;
    int p = 11;
    for (int k = 0; k < 11; ++k)
        for (int l = k; l < 11; ++l) {
            double Me = gs[p] * invE; ++p;
            double term = Me * wv[k] * wv[l];
            s2 += (k == l) ? term : 2.0 * term;
        }
    double var = s2 - md * md;
    double mu = md + (double)B[c];
    float scale = (float)((double)G[c] / sqrt(var + (double)EPS_BN));
    float shift = (float)((double)BE[c] - mu * (double)scale);

    float* wpd = wbp + layer * 768;
    for (int k = 0; k < 11; ++k) wpd[k * 64 + c] = W[k * 64 + c] * scale;
    wpd[704 + c] = fmaf(B[c], scale, shift);
}

// Degree-bucket counting sort (DESCENDING: heavy nodes first -> LPT schedule).
__global__ void __launch_bounds__(256) bucketA_kernel(
    const int* __restrict__ rowptr, int* __restrict__ pr, int* __restrict__ bhT)
{
    __shared__ int lh[64];
    int t = threadIdx.x, b = blockIdx.x;
    if (t < 64) lh[t] = 0;
    __syncthreads();
    int n = b * 256 + t;
    if (n < NN) {
        int d = rowptr[n + 1] - rowptr[n];
        int db = d < 63 ? d : 63;
        int bkt = 63 - db;                      // descending degree order
        int lrank = atomicAdd(&lh[bkt], 1);     // LDS atomic: block-local only
        pr[n] = (lrank << 6) | bkt;
    }
    __syncthreads();
    if (t < 64) bhT[t * SCAN_BLOCKS + b] = lh[t];   // bucket-major layout
}

// Generic exclusive scan over bhT (bucket-major => scan yields global offsets).
__global__ void __launch_bounds__(256) gscanA_kernel(
    int* __restrict__ a, int* __restrict__ gbsum)
{
    int b = blockIdx.x, t = threadIdx.x;
    int i = b * 256 + t;
    int d = (i < GS_LEN) ? a[i] : 0;
    __shared__ int sh[256];
    sh[t] = d;
    __syncthreads();
    for (int off = 1; off < 256; off <<= 1) {
        int val = (t >= off) ? sh[t - off] : 0;
        __syncthreads();
        sh[t] += val;
        __syncthreads();
    }
    if (i < GS_LEN) a[i] = sh[t] - d;
    if (t == 255) gbsum[b] = sh[255];
}

__global__ void __launch_bounds__(256) gscanB_kernel(
    int* __restrict__ a, const int* __restrict__ gbsum)
{
    int b = blockIdx.x, t = threadIdx.x;
    __shared__ int sh[256];
    int s = 0;
    for (int j = t; j < b; j += 256) s += gbsum[j];
    sh[t] = s;
    __syncthreads();
    for (int off = 128; off > 0; off >>= 1) {
        if (t < off) sh[t] += sh[t + off];
        __syncthreads();
    }
    int boff = sh[0];
    int i = b * 256 + t;
    if (i < GS_LEN) a[i] += boff;
}

// Emit int4 perm records {node, rowptr[n], rowptr[n+1], 0}.
__global__ void __launch_bounds__(256) permB_kernel(
    const int* __restrict__ pr, const int* __restrict__ bhT,
    const int* __restrict__ rowptr, int4* __restrict__ perm4)
{
    int n = blockIdx.x * 256 + threadIdx.x;
    if (n >= NN) return;
    int p = pr[n];
    int bkt = p & 63, lrank = p >> 6, b = n >> 8;
    int pos = bhT[bkt * SCAN_BLOCKS + b] + lrank;
    perm4[pos] = make_int4(n, rowptr[n], rowptr[n + 1], 0);
}

// THIN per-edge body (reconstructs e from vres gathers).
#define EDGE_BODY(RR, XI, SA, SB)                                            \
    do {                                                                     \
        unsigned p_ = (unsigned)((RR) >> 32);                                \
        float e_[11];                                                        \
        e_[0] = __uint_as_float(p_ & 0xffff0000u);                           \
        e_[1] = __uint_as_float(p_ << 16);                                   \
        float df_[8];                                                        \
        df_[0] = vd[0] - (SA).x; df_[1] = vd[1] - (SA).y;                    \
        df_[2] = vd[2] - (SA).z; df_[3] = vd[3] - (SA).w;                    \
        df_[4] = vd[4] - (SB).x; df_[5] = vd[5] - (SB).y;                    \
        df_[6] = vd[6] - (SB).z; df_[7] = vd[7] - (SB).w;                    \
        float nsq_ = 0.0f;                                                   \
        _Pragma("unroll")                                                    \
        for (int q = 0; q < 8; ++q) nsq_ = fmaf(df_[q], df_[q], nsq_);       \
        float nrm_ = sqrtf(nsq_);                                            \
        float invn_ = __builtin_amdgcn_rcpf(nrm_ + EPS_NORM);                \
        e_[2] = nrm_;                                                        \
        _Pragma("unroll")                                                    \
        for (int q = 0; q < 8; ++q) e_[3 + q] = df_[q] * invn_;              \
        _Pragma("unroll")                                                    \
        for (int o = 0; o < 8; ++o) {                                        \
            float hh_ = breg[o];                                             \
            _Pragma("unroll")                                                \
            for (int k = 0; k < 11; ++k) hh_ = fmaf(e_[k], wreg[k][o], hh_); \
            msg[o] = fmaf((XI), fast_tanh(hh_), msg[o]);                     \
        }                                                                    \
    } while (0)

// FAT per-edge body (e preunpacked from fp16 record).
#define FAT_BODY(LO, HI, XI)                                                 \
    do {                                                                     \
        float2 e01_ = upk2((LO).x), e23_ = upk2((LO).y);                     \
        float2 e45_ = upk2((LO).z), e67_ = upk2((LO).w);                     \
        float2 e89_ = upk2((HI).x), eAx_ = upk2((HI).y);                     \
        float e_[11] = {e01_.x, e01_.y, e23_.x, e23_.y, e45_.x, e45_.y,      \
                        e67_.x, e67_.y, e89_.x, e89_.y, eAx_.x};             \
        _Pragma("unroll")                                                    \
        for (int o = 0; o < 8; ++o) {                                        \
            float hh_ = breg[o];                                             \
            _Pragma("unroll")                                                \
            for (int k = 0; k < 11; ++k) hh_ = fmaf(e_[k], wreg[k][o], hh_); \
            msg[o] = fmaf((XI), fast_tanh(hh_), msg[o]);                     \
        }                                                                    \
    } while (0)

// Shared epilogue: lane-group reduce + mean + root matmul + lrelu (+res).
#define LAYER_EPILOGUE                                                       \
    _Pragma("unroll")                                                        \
    for (int o = 0; o < 8; ++o) {                                            \
        float m = msg[o];                                                    \
        m += __shfl_xor(m, 1);                                               \
        m += __shfl_xor(m, 2);                                               \
        m += __shfl_xor(m, 4);                                               \
        msg[o] = m;                                                          \
    }                                                                        \
    float mo = msg[0];                                                       \
    _Pragma("unroll")                                                        \
    for (int o = 1; o < 8; ++o) if (i == o) mo = msg[o];                     \
    float cf = (float)(rp1 - rp0);                                           \
    float invc = __builtin_amdgcn_rcpf(fmaxf(cf, 1.0f));                     \
    float xn[8];                                                             \
    if (LAYER == 0) {                                                        \
        _Pragma("unroll")                                                    \
        for (int q = 0; q < 8; ++q) xn[q] = vd[q];                           \
    } else {                                                                 \
        float4 x0 = *(const float4*)(x + (size_t)n * 8);                     \
        float4 x1 = *(const float4*)(x + (size_t)n * 8 + 4);                 \
        xn[0] = x0.x; xn[1] = x0.y; xn[2] = x0.z; xn[3] = x0.w;              \
        xn[4] = x1.x; xn[5] = x1.y; xn[6] = x1.z; xn[7] = x1.w;              \
    }                                                                        \
    float a = fmaf(mo, invc, rb[i]);                                         \
    _Pragma("unroll")                                                        \
    for (int k = 0; k < 8; ++k) a = fmaf(xn[k], rw[k * 8 + i], a);           \
    float y = (a > 0.0f) ? a : SLOPE * a;                                    \
    if (LAYER == 1) y += vres[(size_t)n * 8 + i];                            \
    out[(size_t)n * 8 + i] = y;

#define LAYER_PROLOGUE                                                       \
    int g = blockIdx.x * 256 + threadIdx.x;                                  \
    int4 pm = perm4[g >> 3];                                                 \
    int n = pm.x, rp0 = pm.y, rp1 = pm.z;                                    \
    int i = g & 7;                                                           \
    float wreg[11][8];                                                       \
    _Pragma("unroll")                                                        \
    for (int k = 0; k < 11; ++k) {                                           \
        float4 wa = *(const float4*)(wb + k * 64 + i * 8);                   \
        float4 wc = *(const float4*)(wb + k * 64 + i * 8 + 4);               \
        wreg[k][0] = wa.x; wreg[k][1] = wa.y; wreg[k][2] = wa.z;             \
        wreg[k][3] = wa.w; wreg[k][4] = wc.x; wreg[k][5] = wc.y;             \
        wreg[k][6] = wc.z; wreg[k][7] = wc.w;                                \
    }                                                                        \
    float breg[8];                                                           \
    {                                                                        \
        float4 ba = *(const float4*)(wb + 704 + i * 8);                      \
        float4 bb = *(const float4*)(wb + 704 + i * 8 + 4);                  \
        breg[0] = ba.x; breg[1] = ba.y; breg[2] = ba.z; breg[3] = ba.w;      \
        breg[4] = bb.x; breg[5] = bb.y; breg[6] = bb.z; breg[7] = bb.w;      \
    }                                                                        \
    float4 vd0 = *(const float4*)(vres + (size_t)n * 8);                     \
    float4 vd1 = *(const float4*)(vres + (size_t)n * 8 + 4);                 \
    float vd[8] = {vd0.x, vd0.y, vd0.z, vd0.w, vd1.x, vd1.y, vd1.z, vd1.w};  \
    float msg[8];                                                            \
    _Pragma("unroll")                                                        \
    for (int o = 0; o < 8; ++o) msg[o] = 0.0f;

// FAT layer: stream fp16-e records; only x[src] gathered (4B, L2).
template<int LAYER>
__global__ void __launch_bounds__(256) layer_fat_kernel(
    const float* __restrict__ vres,
    const float* __restrict__ x,
    const uint4* __restrict__ recsF,
    const int4* __restrict__ perm4,
    const float* __restrict__ wb,
    const float* __restrict__ rw, const float* __restrict__ rb,
    float* __restrict__ out)
{
    LAYER_PROLOGUE
    int j = rp0;
    for (; j + 2 <= rp1; j += 2) {
        uint4 lo0 = recsF[(size_t)j * 2],     hi0 = recsF[(size_t)j * 2 + 1];
        uint4 lo1 = recsF[(size_t)j * 2 + 2], hi1 = recsF[(size_t)j * 2 + 3];
        float xi0 = x[(size_t)(int)hi0.z * 8 + i];
        float xi1 = x[(size_t)(int)hi1.z * 8 + i];
        FAT_BODY(lo0, hi0, xi0);
        FAT_BODY(lo1, hi1, xi1);
    }
    if (j < rp1) {
        uint4 lo0 = recsF[(size_t)j * 2], hi0 = recsF[(size_t)j * 2 + 1];
        float xi0 = x[(size_t)(int)hi0.z * 8 + i];
        FAT_BODY(lo0, hi0, xi0);
    }
    LAYER_EPILOGUE
}

// THIN layer (fallback when ws too small): gathers vres rows per edge.
template<int LAYER>
__global__ void __launch_bounds__(256) layer_thin_kernel(
    const float* __restrict__ vres,
    const float* __restrict__ x,
    const unsigned long long* __restrict__ recs,
    const int4* __restrict__ perm4,
    const float* __restrict__ wb,
    const float* __restrict__ rw, const float* __restrict__ rb,
    float* __restrict__ out)
{
    LAYER_PROLOGUE
    int j = rp0;
    for (; j + 2 <= rp1; j += 2) {
        unsigned long long r0 = recs[j];
        unsigned long long r1 = recs[j + 1];
        int s0i = (int)(unsigned)r0;
        int s1i = (int)(unsigned)r1;
        float xi0 = x[(size_t)s0i * 8 + i];
        float xi1 = x[(size_t)s1i * 8 + i];
        float4 s00 = *(const float4*)(vres + (size_t)s0i * 8);
        float4 s01 = *(const float4*)(vres + (size_t)s0i * 8 + 4);
        float4 s10 = *(const float4*)(vres + (size_t)s1i * 8);
        float4 s11 = *(const float4*)(vres + (size_t)s1i * 8 + 4);
        EDGE_BODY(r0, xi0, s00, s01);
        EDGE_BODY(r1, xi1, s10, s11);
    }
    if (j < rp1) {
        unsigned long long r0 = recs[j];
        int s0i = (int)(unsigned)r0;
        float xi0 = x[(size_t)s0i * 8 + i];
        float4 s00 = *(const float4*)(vres + (size_t)s0i * 8);
        float4 s01 = *(const float4*)(vres + (size_t)s0i * 8 + 4);
        EDGE_BODY(r0, xi0, s00, s01);
    }
    LAYER_EPILOGUE
}

extern "C" void kernel_launch(void* const* d_in, const int* in_sizes, int n_in,
                              void* d_out, int out_size, void* d_ws, size_t ws_size,
                              hipStream_t stream) {
    const float* v  = (const float*)d_in[0];
    const int* ei   = (const int*)d_in[1];
    const float* ea = (const float*)d_in[2];
    const float* en_w0  = (const float*)d_in[3];
    const float* en_b0  = (const float*)d_in[4];
    const float* en_g0  = (const float*)d_in[5];
    const float* en_be0 = (const float*)d_in[6];
    const float* rw0    = (const float*)d_in[7];
    const float* rb0    = (const float*)d_in[8];
    const float* en_w1  = (const float*)d_in[9];
    const float* en_b1  = (const float*)d_in[10];
    const float* en_g1  = (const float*)d_in[11];
    const float* en_be1 = (const float*)d_in[12];
    const float* rw1    = (const float*)d_in[13];
    const float* rb1    = (const float*)d_in[14];

    char* ws = (char*)d_ws;
    float* partials = (float*)(ws);                   // 1024*77*4 = 315,392 B
    float* wbp      = (float*)(ws + 327680);          // 6,144 B
    int*   deg      = (int*)  (ws + 335872);          // 400,000 B
    int*   rowptr   = (int*)  (ws + 737280);          // 400,004 B
    int*   bsum     = (int*)  (ws + 1138688);         // 1,564 B
    int*   pr       = (int*)  (ws + 1142784);         // 400,000 B
    int4*  perm4    = (int4*) (ws + 1544192);         // 1,600,000 B
    int*   cursor   = (int*)  (ws + 3145728);         // 400,000 B
    int*   bhT      = (int*)  (ws + 3547136);         // 100,096 B
    int*   gbsum    = (int*)  (ws + 3647488);         // 392 B
    float* v1       = (float*)(ws + 3649536);         // 3,200,000 B
    unsigned long long* recs = (unsigned long long*)(ws + 6850560); // thin: 12.8 MB
    uint4* recsF    = (uint4*)(ws + 6850560);         // fat: 51.2 MB (end ~58 MB)
    float* vout     = (float*)d_out;

    const bool fat = (ws_size >= FAT_WS_NEEDED);

    (void)hipMemsetAsync(deg, 0, NN * sizeof(int), stream);

    deg_kernel<<<(NE / 4 + 255) / 256, 256, 0, stream>>>(ei, deg);
    scanA_kernel<<<SCAN_BLOCKS, 256, 0, stream>>>(deg, rowptr, bsum);
    scanC_kernel<<<SCAN_BLOCKS, 256, 0, stream>>>(rowptr, bsum, cursor);
    if (fat) {
        scatstat_kernel<true><<<STATS_BLOCKS, STATS_THREADS, 0, stream>>>(
            v, ei, ea, cursor, recs, recsF, partials);
    } else {
        scatstat_kernel<false><<<STATS_BLOCKS, STATS_THREADS, 0, stream>>>(
            v, ei, ea, cursor, recs, recsF, partials);
    }
    bn_finalize_kernel<<<1, 128, 0, stream>>>(partials, en_w0, en_b0, en_g0, en_be0,
                                              en_w1, en_b1, en_g1, en_be1, wbp);
    bucketA_kernel<<<SCAN_BLOCKS, 256, 0, stream>>>(rowptr, pr, bhT);
    gscanA_kernel<<<GS_BLOCKS, 256, 0, stream>>>(bhT, gbsum);
    gscanB_kernel<<<GS_BLOCKS, 256, 0, stream>>>(bhT, gbsum);
    permB_kernel<<<SCAN_BLOCKS, 256, 0, stream>>>(pr, bhT, rowptr, perm4);

    const int LB = (NN * 8) / 256;   // 3125, exact
    if (fat) {
        layer_fat_kernel<0><<<LB, 256, 0, stream>>>(v, v,  recsF, perm4, wbp,       rw0, rb0, v1);
        layer_fat_kernel<1><<<LB, 256, 0, stream>>>(v, v1, recsF, perm4, wbp + 768, rw1, rb1, vout);
    } else {
        layer_thin_kernel<0><<<LB, 256, 0, stream>>>(v, v,  recs, perm4, wbp,       rw0, rb0, v1);
        layer_thin_kernel<1><<<LB, 256, 0, stream>>>(v, v1, recs, perm4, wbp + 768, rw1, rb1, vout);
    }
}

// Round 11
// 394.434 us; speedup vs baseline: 1.1562x; 1.1126x over previous
//
#include <hip/hip_runtime.h>
#include <hip/hip_fp16.h>
#include <math.h>

#define NN 100000
#define NE 1600000
#define EPS_BN 1e-5f
#define EPS_NORM 1e-12f
#define SLOPE 0.01f
#define STATS_BLOCKS 1024
#define STATS_THREADS 512
#define EXP_BLOCKS 1024
#define SCAN_BLOCKS ((NN + 255) / 256)       // 391
#define GS_LEN (64 * SCAN_BLOCKS)            // 25024
#define GS_BLOCKS ((GS_LEN + 255) / 256)     // 98
#define FAT_WS_NEEDED 58050560ULL
#define NEW_WS_NEEDED 70850560ULL

__device__ __forceinline__ float fast_tanh(float x) {
    float t = exp2f(x * 2.885390082f);
    return fmaf(-2.0f, __builtin_amdgcn_rcpf(t + 1.0f), 1.0f);
}

__device__ __forceinline__ unsigned pk2(float a, float b) {
    union { __half2 h; unsigned u; } c;
    c.h = __float22half2_rn(make_float2(a, b));
    return c.u;
}
__device__ __forceinline__ float2 upk2(unsigned u) {
    union { unsigned u; __half2 h; } c; c.u = u;
    return __half22float2(c.h);
}

// Pass 0 (new): in-degree + stable rank per edge.
__global__ void __launch_bounds__(256) deg_rank_kernel(
    const int* __restrict__ ei, int* __restrict__ deg, int* __restrict__ rank)
{
    int e = blockIdx.x * 256 + threadIdx.x;
    if (e >= NE) return;
    int d = ei[NE + e];
    rank[e] = atomicAdd(&deg[d], 1);
}

// Pass 0 (fallback): in-degree only.
__global__ void __launch_bounds__(256) deg_kernel(
    const int* __restrict__ ei, int* __restrict__ deg)
{
    int t = blockIdx.x * 256 + threadIdx.x;
    if (t * 4 >= NE) return;
    int4 d4 = *(const int4*)(ei + NE + t * 4);
    atomicAdd(&deg[d4.x], 1);
    atomicAdd(&deg[d4.y], 1);
    atomicAdd(&deg[d4.z], 1);
    atomicAdd(&deg[d4.w], 1);
}

// Pass 1a: per-block exclusive scan of deg -> rowptr (block-local) + block sums.
__global__ void __launch_bounds__(256) scanA_kernel(
    const int* __restrict__ deg, int* __restrict__ rowptr, int* __restrict__ bsum)
{
    int b = blockIdx.x, t = threadIdx.x;
    int i = b * 256 + t;
    int d = (i < NN) ? deg[i] : 0;
    __shared__ int sh[256];
    sh[t] = d;
    __syncthreads();
    for (int off = 1; off < 256; off <<= 1) {
        int val = (t >= off) ? sh[t - off] : 0;
        __syncthreads();
        sh[t] += val;
        __syncthreads();
    }
    if (i < NN) rowptr[i] = sh[t] - d;
    if (t == 255) bsum[b] = sh[255];
}

// Pass 1b: add block offsets in-place; also emit cursor copy (fallback path).
__global__ void __launch_bounds__(256) scanC_kernel(
    int* __restrict__ rowptr, const int* __restrict__ bsum, int* __restrict__ cursor)
{
    int b = blockIdx.x, t = threadIdx.x;
    __shared__ int sh[256];
    int s = 0;
    for (int j = t; j < b; j += 256) s += bsum[j];
    sh[t] = s;
    __syncthreads();
    for (int off = 128; off > 0; off >>= 1) {
        if (t < off) sh[t] += sh[t + off];
        __syncthreads();
    }
    int boff = sh[0];
    int i = b * 256 + t;
    if (i < NN) {
        int r = rowptr[i] + boff;
        rowptr[i] = r;
        cursor[i] = r;
    }
    if (b == 0 && t == 0) rowptr[NN] = NE;
}

// Pass 2 (new): scatter ONLY 8B thin records {src, fp16x2 attr}; no atomics.
__global__ void __launch_bounds__(256) thin_scatter_kernel(
    const int* __restrict__ ei, const float* __restrict__ ea,
    const int* __restrict__ rowptr, const int* __restrict__ rank,
    unsigned long long* __restrict__ recs8)
{
    int e = blockIdx.x * 256 + threadIdx.x;
    if (e >= NE) return;
    int s = ei[e];
    int d = ei[NE + e];
    float2 a2 = *(const float2*)(ea + 2 * (size_t)e);
    unsigned pk = pk2(a2.x, a2.y);
    int pos = rowptr[d] + rank[e];
    recs8[pos] = ((unsigned long long)pk << 32) | (unsigned)s;
}

// Pass 3 (new): sequential expand thin->fat (fp16 e[11]) + fused e-moment stats.
// 4 threads per node, perm order for balance; fat writes are coalesced.
__global__ void __launch_bounds__(256) expand_stats_kernel(
    const float* __restrict__ v,
    const unsigned long long* __restrict__ recs8,
    const int4* __restrict__ perm4,
    uint4* __restrict__ recsF,
    float* __restrict__ partials)   // [EXP_BLOCKS][77]
{
    float acc[77];
#pragma unroll
    for (int i = 0; i < 77; ++i) acc[i] = 0.0f;

    int tid0 = blockIdx.x * 256 + threadIdx.x;
    for (int g = tid0; g < NN * 4; g += EXP_BLOCKS * 256) {
        int4 pm = perm4[g >> 2];
        int lane = g & 3;
        int n = pm.x, rp0 = pm.y, rp1 = pm.z;
        float4 d0 = *(const float4*)(v + (size_t)n * 8);
        float4 d1 = *(const float4*)(v + (size_t)n * 8 + 4);
        float vd[8] = {d0.x, d0.y, d0.z, d0.w, d1.x, d1.y, d1.z, d1.w};
        for (int j = rp0 + lane; j < rp1; j += 4) {
            unsigned long long r8 = recs8[j];
            int s = (int)(unsigned)r8;
            float2 a2 = upk2((unsigned)(r8 >> 32));
            float4 s0 = *(const float4*)(v + (size_t)s * 8);
            float4 s1 = *(const float4*)(v + (size_t)s * 8 + 4);
            float df[8];
            df[0] = vd[0] - s0.x; df[1] = vd[1] - s0.y;
            df[2] = vd[2] - s0.z; df[3] = vd[3] - s0.w;
            df[4] = vd[4] - s1.x; df[5] = vd[5] - s1.y;
            df[6] = vd[6] - s1.z; df[7] = vd[7] - s1.w;
            float nsq = 0.0f;
#pragma unroll
            for (int q = 0; q < 8; ++q) nsq = fmaf(df[q], df[q], nsq);
            float nrm = sqrtf(nsq);
            float inv = __builtin_amdgcn_rcpf(nrm + EPS_NORM);
            float e[11];
            e[0] = a2.x; e[1] = a2.y; e[2] = nrm;
#pragma unroll
            for (int q = 0; q < 8; ++q) e[3 + q] = df[q] * inv;

            int p = 11;
#pragma unroll
            for (int k = 0; k < 11; ++k) {
                acc[k] += e[k];
#pragma unroll
                for (int l = k; l < 11; ++l) { acc[p] = fmaf(e[k], e[l], acc[p]); ++p; }
            }

            uint4 lo, hi;
            lo.x = pk2(e[0], e[1]); lo.y = pk2(e[2], e[3]);
            lo.z = pk2(e[4], e[5]); lo.w = pk2(e[6], e[7]);
            hi.x = pk2(e[8], e[9]); hi.y = pk2(e[10], 0.0f);
            hi.z = (unsigned)s;     hi.w = 0u;
            recsF[(size_t)j * 2]     = lo;
            recsF[(size_t)j * 2 + 1] = hi;
        }
    }

#pragma unroll
    for (int i = 0; i < 77; ++i) {
        float x = acc[i];
        for (int off = 32; off > 0; off >>= 1) x += __shfl_down(x, off);
        acc[i] = x;
    }
    __shared__ float lsum[4][77];
    int wave = threadIdx.x >> 6;
    int lane = threadIdx.x & 63;
    if (lane == 0) {
#pragma unroll
        for (int i = 0; i < 77; ++i) lsum[wave][i] = acc[i];
    }
    __syncthreads();
    if (threadIdx.x < 77) {
        float t = lsum[0][threadIdx.x] + lsum[1][threadIdx.x]
                + lsum[2][threadIdx.x] + lsum[3][threadIdx.x];
        partials[blockIdx.x * 77 + threadIdx.x] = t;
    }
}

// Fallback pass 2: fused scatter+stats writing fat records directly (round-10).
__global__ void __launch_bounds__(STATS_THREADS) scatstat_kernel(
    const float* __restrict__ v,
    const int* __restrict__ ei,
    const float* __restrict__ ea,
    int* __restrict__ cursor,
    uint4* __restrict__ recsF,
    float* __restrict__ partials)
{
    float acc[77];
#pragma unroll
    for (int i = 0; i < 77; ++i) acc[i] = 0.0f;

    int tid = blockIdx.x * STATS_THREADS + threadIdx.x;
    int stride = STATS_BLOCKS * STATS_THREADS;
    for (int eidx = tid; eidx < NE; eidx += stride) {
        int s = ei[eidx];
        int d = ei[NE + eidx];
        float2 a2 = *(const float2*)(ea + 2 * (size_t)eidx);
        float4 s0 = *(const float4*)(v + (size_t)s * 8);
        float4 s1 = *(const float4*)(v + (size_t)s * 8 + 4);
        float4 d0 = *(const float4*)(v + (size_t)d * 8);
        float4 d1 = *(const float4*)(v + (size_t)d * 8 + 4);
        float df[8];
        df[0] = d0.x - s0.x; df[1] = d0.y - s0.y;
        df[2] = d0.z - s0.z; df[3] = d0.w - s0.w;
        df[4] = d1.x - s1.x; df[5] = d1.y - s1.y;
        df[6] = d1.z - s1.z; df[7] = d1.w - s1.w;
        float nsq = 0.0f;
#pragma unroll
        for (int i = 0; i < 8; ++i) nsq = fmaf(df[i], df[i], nsq);
        float nrm = sqrtf(nsq);
        float inv = __builtin_amdgcn_rcpf(nrm + EPS_NORM);
        float e[11];
        e[0] = a2.x; e[1] = a2.y; e[2] = nrm;
#pragma unroll
        for (int i = 0; i < 8; ++i) e[3 + i] = df[i] * inv;

        int p = 11;
#pragma unroll
        for (int k = 0; k < 11; ++k) {
            acc[k] += e[k];
#pragma unroll
            for (int l = k; l < 11; ++l) { acc[p] = fmaf(e[k], e[l], acc[p]); ++p; }
        }

        int idx = atomicAdd(&cursor[d], 1);
        uint4 lo, hi;
        lo.x = pk2(e[0], e[1]); lo.y = pk2(e[2], e[3]);
        lo.z = pk2(e[4], e[5]); lo.w = pk2(e[6], e[7]);
        hi.x = pk2(e[8], e[9]); hi.y = pk2(e[10], 0.0f);
        hi.z = (unsigned)s;     hi.w = 0u;
        recsF[(size_t)idx * 2]     = lo;
        recsF[(size_t)idx * 2 + 1] = hi;
    }

#pragma unroll
    for (int i = 0; i < 77; ++i) {
        float x = acc[i];
        for (int off = 32; off > 0; off >>= 1) x += __shfl_down(x, off);
        acc[i] = x;
    }
    __shared__ float lsum[8][77];
    int wave = threadIdx.x >> 6;
    int lane = threadIdx.x & 63;
    if (lane == 0) {
#pragma unroll
        for (int i = 0; i < 77; ++i) lsum[wave][i] = acc[i];
    }
    __syncthreads();
    if (threadIdx.x < 77) {
        float t = 0.0f;
#pragma unroll
        for (int w = 0; w < 8; ++w) t += lsum[w][threadIdx.x];
        partials[blockIdx.x * 77 + threadIdx.x] = t;
    }
}

// BN closed-form from moments; fold scale into W' and b'.
__global__ void bn_finalize_kernel(
    const float* __restrict__ partials,
    const float* __restrict__ w0, const float* __restrict__ b0,
    const float* __restrict__ g0, const float* __restrict__ be0,
    const float* __restrict__ w1, const float* __restrict__ b1,
    const float* __restrict__ g1, const float* __restrict__ be1,
    float* __restrict__ wbp)
{
    __shared__ double gs[77];
    int t = threadIdx.x;
    if (t < 77) {
        double s = 0.0;
        for (int b = 0; b < STATS_BLOCKS; b += 4) {
            s += (double)partials[b * 77 + t] + (double)partials[(b + 1) * 77 + t]
               + (double)partials[(b + 2) * 77 + t] + (double)partials[(b + 3) * 77 + t];
        }
        gs[t] = s;
    }
    __syncthreads();
    if (t >= 128) return;
    int layer = t >> 6;
    int c = t & 63;
    const float* W  = layer ? w1 : w0;
    const float* B  = layer ? b1 : b0;
    const float* G  = layer ? g1 : g0;
    const float* BE = layer ? be1 : be0;

    const double invE = 1.0 / (double)NE;
    double m[11], wv[11];
    for (int k = 0; k < 11; ++k) {
        m[k] = gs[k] * invE;
        wv[k] = (double)W[k * 64 + c];
    }
    double md = 0.0;
    for (int k = 0; k < 11; ++k) md += m[k] * wv[k];
    double s2 = 0.0;
    int p = 11;
    for (int k = 0; k < 11; ++k)
        for (int l = k; l < 11; ++l) {
            double Me = gs[p] * invE; ++p;
            double term = Me * wv[k] * wv[l];
            s2 += (k == l) ? term : 2.0 * term;
        }
    double var = s2 - md * md;
    double mu = md + (double)B[c];
    float scale = (float)((double)G[c] / sqrt(var + (double)EPS_BN));
    float shift = (float)((double)BE[c] - mu * (double)scale);

    float* wpd = wbp + layer * 768;
    for (int k = 0; k < 11; ++k) wpd[k * 64 + c] = W[k * 64 + c] * scale;
    wpd[704 + c] = fmaf(B[c], scale, shift);
}

// Degree-bucket counting sort (DESC: heavy nodes first).
__global__ void __launch_bounds__(256) bucketA_kernel(
    const int* __restrict__ rowptr, int* __restrict__ pr, int* __restrict__ bhT)
{
    __shared__ int lh[64];
    int t = threadIdx.x, b = blockIdx.x;
    if (t < 64) lh[t] = 0;
    __syncthreads();
    int n = b * 256 + t;
    if (n < NN) {
        int d = rowptr[n + 1] - rowptr[n];
        int db = d < 63 ? d : 63;
        int bkt = 63 - db;
        int lrank = atomicAdd(&lh[bkt], 1);
        pr[n] = (lrank << 6) | bkt;
    }
    __syncthreads();
    if (t < 64) bhT[t * SCAN_BLOCKS + b] = lh[t];
}

__global__ void __launch_bounds__(256) gscanA_kernel(
    int* __restrict__ a, int* __restrict__ gbsum)
{
    int b = blockIdx.x, t = threadIdx.x;
    int i = b * 256 + t;
    int d = (i < GS_LEN) ? a[i] : 0;
    __shared__ int sh[256];
    sh[t] = d;
    __syncthreads();
    for (int off = 1; off < 256; off <<= 1) {
        int val = (t >= off) ? sh[t - off] : 0;
        __syncthreads();
        sh[t] += val;
        __syncthreads();
    }
    if (i < GS_LEN) a[i] = sh[t] - d;
    if (t == 255) gbsum[b] = sh[255];
}

__global__ void __launch_bounds__(256) gscanB_kernel(
    int* __restrict__ a, const int* __restrict__ gbsum)
{
    int b = blockIdx.x, t = threadIdx.x;
    __shared__ int sh[256];
    int s = 0;
    for (int j = t; j < b; j += 256) s += gbsum[j];
    sh[t] = s;
    __syncthreads();
    for (int off = 128; off > 0; off >>= 1) {
        if (t < off) sh[t] += sh[t + off];
        __syncthreads();
    }
    int boff = sh[0];
    int i = b * 256 + t;
    if (i < GS_LEN) a[i] += boff;
}

__global__ void __launch_bounds__(256) permB_kernel(
    const int* __restrict__ pr, const int* __restrict__ bhT,
    const int* __restrict__ rowptr, int4* __restrict__ perm4)
{
    int n = blockIdx.x * 256 + threadIdx.x;
    if (n >= NN) return;
    int p = pr[n];
    int bkt = p & 63, lrank = p >> 6, b = n >> 8;
    int pos = bhT[bkt * SCAN_BLOCKS + b] + lrank;
    perm4[pos] = make_int4(n, rowptr[n], rowptr[n + 1], 0);
}

#define FAT_BODY(LO, HI, XI)                                                 \
    do {                                                                     \
        float2 e01_ = upk2((LO).x), e23_ = upk2((LO).y);                     \
        float2 e45_ = upk2((LO).z), e67_ = upk2((LO).w);                     \
        float2 e89_ = upk2((HI).x), eAx_ = upk2((HI).y);                     \
        float e_[11] = {e01_.x, e01_.y, e23_.x, e23_.y, e45_.x, e45_.y,      \
                        e67_.x, e67_.y, e89_.x, e89_.y, eAx_.x};             \
        _Pragma("unroll")                                                    \
        for (int o = 0; o < 8; ++o) {                                        \
            float hh_ = breg[o];                                             \
            _Pragma("unroll")                                                \
            for (int k = 0; k < 11; ++k) hh_ = fmaf(e_[k], wreg[k][o], hh_); \
            msg[o] = fmaf((XI), fast_tanh(hh_), msg[o]);                     \
        }                                                                    \
    } while (0)

// Per-layer fused gather-message + mean + root + lrelu (+residual).
template<int LAYER>
__global__ void __launch_bounds__(256) layer_fat_kernel(
    const float* __restrict__ vres,
    const float* __restrict__ x,
    const uint4* __restrict__ recsF,
    const int4* __restrict__ perm4,
    const float* __restrict__ wb,
    const float* __restrict__ rw, const float* __restrict__ rb,
    float* __restrict__ out)
{
    int g = blockIdx.x * 256 + threadIdx.x;
    int4 pm = perm4[g >> 3];
    int n = pm.x, rp0 = pm.y, rp1 = pm.z;
    int i = g & 7;

    float wreg[11][8];
#pragma unroll
    for (int k = 0; k < 11; ++k) {
        float4 wa = *(const float4*)(wb + k * 64 + i * 8);
        float4 wc = *(const float4*)(wb + k * 64 + i * 8 + 4);
        wreg[k][0] = wa.x; wreg[k][1] = wa.y; wreg[k][2] = wa.z; wreg[k][3] = wa.w;
        wreg[k][4] = wc.x; wreg[k][5] = wc.y; wreg[k][6] = wc.z; wreg[k][7] = wc.w;
    }
    float breg[8];
    {
        float4 ba = *(const float4*)(wb + 704 + i * 8);
        float4 bb = *(const float4*)(wb + 704 + i * 8 + 4);
        breg[0] = ba.x; breg[1] = ba.y; breg[2] = ba.z; breg[3] = ba.w;
        breg[4] = bb.x; breg[5] = bb.y; breg[6] = bb.z; breg[7] = bb.w;
    }

    float4 vd0 = *(const float4*)(vres + (size_t)n * 8);
    float4 vd1 = *(const float4*)(vres + (size_t)n * 8 + 4);
    float vd[8] = {vd0.x, vd0.y, vd0.z, vd0.w, vd1.x, vd1.y, vd1.z, vd1.w};

    float msg[8];
#pragma unroll
    for (int o = 0; o < 8; ++o) msg[o] = 0.0f;

    int j = rp0;
    for (; j + 2 <= rp1; j += 2) {
        uint4 lo0 = recsF[(size_t)j * 2],     hi0 = recsF[(size_t)j * 2 + 1];
        uint4 lo1 = recsF[(size_t)j * 2 + 2], hi1 = recsF[(size_t)j * 2 + 3];
        float xi0 = x[(size_t)(int)hi0.z * 8 + i];
        float xi1 = x[(size_t)(int)hi1.z * 8 + i];
        FAT_BODY(lo0, hi0, xi0);
        FAT_BODY(lo1, hi1, xi1);
    }
    if (j < rp1) {
        uint4 lo0 = recsF[(size_t)j * 2], hi0 = recsF[(size_t)j * 2 + 1];
        float xi0 = x[(size_t)(int)hi0.z * 8 + i];
        FAT_BODY(lo0, hi0, xi0);
    }

#pragma unroll
    for (int o = 0; o < 8; ++o) {
        float m = msg[o];
        m += __shfl_xor(m, 1);
        m += __shfl_xor(m, 2);
        m += __shfl_xor(m, 4);
        msg[o] = m;
    }
    float mo = msg[0];
#pragma unroll
    for (int o = 1; o < 8; ++o) if (i == o) mo = msg[o];

    float cf = (float)(rp1 - rp0);
    float invc = __builtin_amdgcn_rcpf(fmaxf(cf, 1.0f));

    float xn[8];
    if (LAYER == 0) {
#pragma unroll
        for (int q = 0; q < 8; ++q) xn[q] = vd[q];
    } else {
        float4 x0 = *(const float4*)(x + (size_t)n * 8);
        float4 x1 = *(const float4*)(x + (size_t)n * 8 + 4);
        xn[0] = x0.x; xn[1] = x0.y; xn[2] = x0.z; xn[3] = x0.w;
        xn[4] = x1.x; xn[5] = x1.y; xn[6] = x1.z; xn[7] = x1.w;
    }
    float a = fmaf(mo, invc, rb[i]);
#pragma unroll
    for (int k = 0; k < 8; ++k) a = fmaf(xn[k], rw[k * 8 + i], a);
    float y = (a > 0.0f) ? a : SLOPE * a;
    if (LAYER == 1) y += vres[(size_t)n * 8 + i];
    out[(size_t)n * 8 + i] = y;
}

extern "C" void kernel_launch(void* const* d_in, const int* in_sizes, int n_in,
                              void* d_out, int out_size, void* d_ws, size_t ws_size,
                              hipStream_t stream) {
    const float* v  = (const float*)d_in[0];
    const int* ei   = (const int*)d_in[1];
    const float* ea = (const float*)d_in[2];
    const float* en_w0  = (const float*)d_in[3];
    const float* en_b0  = (const float*)d_in[4];
    const float* en_g0  = (const float*)d_in[5];
    const float* en_be0 = (const float*)d_in[6];
    const float* rw0    = (const float*)d_in[7];
    const float* rb0    = (const float*)d_in[8];
    const float* en_w1  = (const float*)d_in[9];
    const float* en_b1  = (const float*)d_in[10];
    const float* en_g1  = (const float*)d_in[11];
    const float* en_be1 = (const float*)d_in[12];
    const float* rw1    = (const float*)d_in[13];
    const float* rb1    = (const float*)d_in[14];

    char* ws = (char*)d_ws;
    float* partials = (float*)(ws);                   // 1024*77*4 = 315,392 B
    float* wbp      = (float*)(ws + 327680);          // 6,144 B
    int*   deg      = (int*)  (ws + 335872);          // 400,000 B
    int*   rowptr   = (int*)  (ws + 737280);          // 400,004 B
    int*   bsum     = (int*)  (ws + 1138688);         // 1,564 B
    int*   pr       = (int*)  (ws + 1142784);         // 400,000 B
    int4*  perm4    = (int4*) (ws + 1544192);         // 1,600,000 B
    int*   cursor   = (int*)  (ws + 3145728);         // 400,000 B
    int*   bhT      = (int*)  (ws + 3547136);         // 100,096 B
    int*   gbsum    = (int*)  (ws + 3647488);         // 392 B
    float* v1       = (float*)(ws + 3649536);         // 3,200,000 B
    uint4* recsF    = (uint4*)(ws + 6850560);         // 51,200,000 B (ends 58,050,560)
    int*   rank     = (int*)  (ws + 6850560);         // 6.4 MB, overlays recsF (dead before expand)
    unsigned long long* recs8 = (unsigned long long*)(ws + 58050560); // 12.8 MB (new path)
    float* vout     = (float*)d_out;

    const bool newpath = (ws_size >= NEW_WS_NEEDED);

    (void)hipMemsetAsync(deg, 0, NN * sizeof(int), stream);

    if (newpath) {
        deg_rank_kernel<<<(NE + 255) / 256, 256, 0, stream>>>(ei, deg, rank);
        scanA_kernel<<<SCAN_BLOCKS, 256, 0, stream>>>(deg, rowptr, bsum);
        scanC_kernel<<<SCAN_BLOCKS, 256, 0, stream>>>(rowptr, bsum, cursor);
        bucketA_kernel<<<SCAN_BLOCKS, 256, 0, stream>>>(rowptr, pr, bhT);
        gscanA_kernel<<<GS_BLOCKS, 256, 0, stream>>>(bhT, gbsum);
        gscanB_kernel<<<GS_BLOCKS, 256, 0, stream>>>(bhT, gbsum);
        permB_kernel<<<SCAN_BLOCKS, 256, 0, stream>>>(pr, bhT, rowptr, perm4);
        thin_scatter_kernel<<<(NE + 255) / 256, 256, 0, stream>>>(ei, ea, rowptr, rank, recs8);
        expand_stats_kernel<<<EXP_BLOCKS, 256, 0, stream>>>(v, recs8, perm4, recsF, partials);
    } else {
        deg_kernel<<<(NE / 4 + 255) / 256, 256, 0, stream>>>(ei, deg);
        scanA_kernel<<<SCAN_BLOCKS, 256, 0, stream>>>(deg, rowptr, bsum);
        scanC_kernel<<<SCAN_BLOCKS, 256, 0, stream>>>(rowptr, bsum, cursor);
        scatstat_kernel<<<STATS_BLOCKS, STATS_THREADS, 0, stream>>>(v, ei, ea, cursor, recsF, partials);
        bucketA_kernel<<<SCAN_BLOCKS, 256, 0, stream>>>(rowptr, pr, bhT);
        gscanA_kernel<<<GS_BLOCKS, 256, 0, stream>>>(bhT, gbsum);
        gscanB_kernel<<<GS_BLOCKS, 256, 0, stream>>>(bhT, gbsum);
        permB_kernel<<<SCAN_BLOCKS, 256, 0, stream>>>(pr, bhT, rowptr, perm4);
    }
    bn_finalize_kernel<<<1, 128, 0, stream>>>(partials, en_w0, en_b0, en_g0, en_be0,
                                              en_w1, en_b1, en_g1, en_be1, wbp);

    const int LB = (NN * 8) / 256;   // 3125, exact
    layer_fat_kernel<0><<<LB, 256, 0, stream>>>(v, v,  recsF, perm4, wbp,       rw0, rb0, v1);
    layer_fat_kernel<1><<<LB, 256, 0, stream>>>(v, v1, recsF, perm4, wbp + 768, rw1, rb1, vout);
}

// Round 12
// 365.445 us; speedup vs baseline: 1.2479x; 1.0793x over previous
//
#include <hip/hip_runtime.h>
#include <hip/hip_fp16.h>
#include <math.h>

#define NN 100000
#define NE 1600000
#define EPS_BN 1e-5f
#define EPS_NORM 1e-12f
#define SLOPE 0.01f
#define STATS_BLOCKS 1024
#define STATS_THREADS 512
#define EXP_BLOCKS 1024
#define SCAN_BLOCKS ((NN + 255) / 256)       // 391
#define GS_LEN (64 * SCAN_BLOCKS)            // 25024
#define GS_BLOCKS ((GS_LEN + 255) / 256)     // 98
#define NEW_WS_NEEDED 70850560ULL

__device__ __forceinline__ float fast_tanh(float x) {
    float t = exp2f(x * 2.885390082f);
    return fmaf(-2.0f, __builtin_amdgcn_rcpf(t + 1.0f), 1.0f);
}

__device__ __forceinline__ unsigned pk2(float a, float b) {
    union { __half2 h; unsigned u; } c;
    c.h = __float22half2_rn(make_float2(a, b));
    return c.u;
}
__device__ __forceinline__ float2 upk2(unsigned u) {
    union { unsigned u; __half2 h; } c; c.u = u;
    return __half22float2(c.h);
}

// Pass 0: in-degree + stable rank per edge.
__global__ void __launch_bounds__(256) deg_rank_kernel(
    const int* __restrict__ ei, int* __restrict__ deg, int* __restrict__ rank)
{
    int e = blockIdx.x * 256 + threadIdx.x;
    if (e >= NE) return;
    int d = ei[NE + e];
    rank[e] = atomicAdd(&deg[d], 1);
}

// Fallback pass 0: degree only.
__global__ void __launch_bounds__(256) deg_kernel(
    const int* __restrict__ ei, int* __restrict__ deg)
{
    int t = blockIdx.x * 256 + threadIdx.x;
    if (t * 4 >= NE) return;
    int4 d4 = *(const int4*)(ei + NE + t * 4);
    atomicAdd(&deg[d4.x], 1);
    atomicAdd(&deg[d4.y], 1);
    atomicAdd(&deg[d4.z], 1);
    atomicAdd(&deg[d4.w], 1);
}

// Pass 1a: per-block exclusive scan of deg -> rowptr + block sums.
__global__ void __launch_bounds__(256) scanA_kernel(
    const int* __restrict__ deg, int* __restrict__ rowptr, int* __restrict__ bsum)
{
    int b = blockIdx.x, t = threadIdx.x;
    int i = b * 256 + t;
    int d = (i < NN) ? deg[i] : 0;
    __shared__ int sh[256];
    sh[t] = d;
    __syncthreads();
    for (int off = 1; off < 256; off <<= 1) {
        int val = (t >= off) ? sh[t - off] : 0;
        __syncthreads();
        sh[t] += val;
        __syncthreads();
    }
    if (i < NN) rowptr[i] = sh[t] - d;
    if (t == 255) bsum[b] = sh[255];
}

// Pass 1b: add block offsets; emit cursor copy (fallback path uses it).
__global__ void __launch_bounds__(256) scanC_kernel(
    int* __restrict__ rowptr, const int* __restrict__ bsum, int* __restrict__ cursor)
{
    int b = blockIdx.x, t = threadIdx.x;
    __shared__ int sh[256];
    int s = 0;
    for (int j = t; j < b; j += 256) s += bsum[j];
    sh[t] = s;
    __syncthreads();
    for (int off = 128; off > 0; off >>= 1) {
        if (t < off) sh[t] += sh[t + off];
        __syncthreads();
    }
    int boff = sh[0];
    int i = b * 256 + t;
    if (i < NN) {
        int r = rowptr[i] + boff;
        rowptr[i] = r;
        cursor[i] = r;
    }
    if (b == 0 && t == 0) rowptr[NN] = NE;
}

// Pass 2: scatter 8B packed record [dst:17|src:17|a0:15|a1:15]; no atomics.
__global__ void __launch_bounds__(256) thin_scatter_kernel(
    const int* __restrict__ ei, const float* __restrict__ ea,
    const int* __restrict__ rowptr, const int* __restrict__ rank,
    unsigned long long* __restrict__ recs8)
{
    int e = blockIdx.x * 256 + threadIdx.x;
    if (e >= NE) return;
    int s = ei[e];
    int d = ei[NE + e];
    float2 a2 = *(const float2*)(ea + 2 * (size_t)e);
    unsigned a0q = __float2uint_rn(a2.x * 32768.0f); if (a0q > 32767u) a0q = 32767u;
    unsigned a1q = __float2uint_rn(a2.y * 32768.0f); if (a1q > 32767u) a1q = 32767u;
    int pos = rowptr[d] + rank[e];
    unsigned long long rec = ((unsigned long long)(unsigned)d << 47)
                           | ((unsigned long long)(unsigned)s << 30)
                           | ((unsigned long long)a0q << 15)
                           | (unsigned long long)a1q;
    recs8[pos] = rec;
}

// Pass 3: EDGE-PARALLEL expand thin->fat (split A16/B16, wave-contiguous
// stores) + fused e-moment stats. Sorted order makes v[dst] near-broadcast.
__global__ void __launch_bounds__(256) expand_stats_kernel(
    const float* __restrict__ v,
    const unsigned long long* __restrict__ recs8,
    uint4* __restrict__ A16, uint4* __restrict__ B16,
    float* __restrict__ partials)   // [EXP_BLOCKS][77]
{
    float acc[77];
#pragma unroll
    for (int i = 0; i < 77; ++i) acc[i] = 0.0f;

    int tid = blockIdx.x * 256 + threadIdx.x;
    for (int eidx = tid; eidx < NE; eidx += EXP_BLOCKS * 256) {
        unsigned long long r = recs8[eidx];
        int d = (int)(r >> 47);
        int s = (int)((r >> 30) & 0x1FFFFu);
        float a0 = (float)(unsigned)((r >> 15) & 0x7FFFu) * (1.0f / 32768.0f);
        float a1 = (float)(unsigned)(r & 0x7FFFu) * (1.0f / 32768.0f);

        float4 s0 = *(const float4*)(v + (size_t)s * 8);
        float4 s1 = *(const float4*)(v + (size_t)s * 8 + 4);
        float4 d0 = *(const float4*)(v + (size_t)d * 8);
        float4 d1 = *(const float4*)(v + (size_t)d * 8 + 4);
        float df[8];
        df[0] = d0.x - s0.x; df[1] = d0.y - s0.y;
        df[2] = d0.z - s0.z; df[3] = d0.w - s0.w;
        df[4] = d1.x - s1.x; df[5] = d1.y - s1.y;
        df[6] = d1.z - s1.z; df[7] = d1.w - s1.w;
        float nsq = 0.0f;
#pragma unroll
        for (int q = 0; q < 8; ++q) nsq = fmaf(df[q], df[q], nsq);
        float nrm = sqrtf(nsq);
        float inv = __builtin_amdgcn_rcpf(nrm + EPS_NORM);
        float e[11];
        e[0] = a0; e[1] = a1; e[2] = nrm;
#pragma unroll
        for (int q = 0; q < 8; ++q) e[3 + q] = df[q] * inv;

        int p = 11;
#pragma unroll
        for (int k = 0; k < 11; ++k) {
            acc[k] += e[k];
#pragma unroll
            for (int l = k; l < 11; ++l) { acc[p] = fmaf(e[k], e[l], acc[p]); ++p; }
        }

        uint4 lo, hi;
        lo.x = pk2(e[0], e[1]); lo.y = pk2(e[2], e[3]);
        lo.z = pk2(e[4], e[5]); lo.w = pk2(e[6], e[7]);
        hi.x = pk2(e[8], e[9]); hi.y = pk2(e[10], 0.0f);
        hi.z = (unsigned)s;     hi.w = 0u;
        A16[eidx] = lo;          // lane-contiguous: 1KB/instr, full lines
        B16[eidx] = hi;
    }

#pragma unroll
    for (int i = 0; i < 77; ++i) {
        float x = acc[i];
        for (int off = 32; off > 0; off >>= 1) x += __shfl_down(x, off);
        acc[i] = x;
    }
    __shared__ float lsum[4][77];
    int wave = threadIdx.x >> 6;
    int lane = threadIdx.x & 63;
    if (lane == 0) {
#pragma unroll
        for (int i = 0; i < 77; ++i) lsum[wave][i] = acc[i];
    }
    __syncthreads();
    if (threadIdx.x < 77) {
        float t = lsum[0][threadIdx.x] + lsum[1][threadIdx.x]
                + lsum[2][threadIdx.x] + lsum[3][threadIdx.x];
        partials[blockIdx.x * 77 + threadIdx.x] = t;
    }
}

// Fallback pass 2: fused cursor-atomic scatter+stats writing A16/B16.
__global__ void __launch_bounds__(STATS_THREADS) scatstat_kernel(
    const float* __restrict__ v,
    const int* __restrict__ ei,
    const float* __restrict__ ea,
    int* __restrict__ cursor,
    uint4* __restrict__ A16, uint4* __restrict__ B16,
    float* __restrict__ partials)
{
    float acc[77];
#pragma unroll
    for (int i = 0; i < 77; ++i) acc[i] = 0.0f;

    int tid = blockIdx.x * STATS_THREADS + threadIdx.x;
    int stride = STATS_BLOCKS * STATS_THREADS;
    for (int eidx = tid; eidx < NE; eidx += stride) {
        int s = ei[eidx];
        int d = ei[NE + eidx];
        float2 a2 = *(const float2*)(ea + 2 * (size_t)eidx);
        float4 s0 = *(const float4*)(v + (size_t)s * 8);
        float4 s1 = *(const float4*)(v + (size_t)s * 8 + 4);
        float4 d0 = *(const float4*)(v + (size_t)d * 8);
        float4 d1 = *(const float4*)(v + (size_t)d * 8 + 4);
        float df[8];
        df[0] = d0.x - s0.x; df[1] = d0.y - s0.y;
        df[2] = d0.z - s0.z; df[3] = d0.w - s0.w;
        df[4] = d1.x - s1.x; df[5] = d1.y - s1.y;
        df[6] = d1.z - s1.z; df[7] = d1.w - s1.w;
        float nsq = 0.0f;
#pragma unroll
        for (int i = 0; i < 8; ++i) nsq = fmaf(df[i], df[i], nsq);
        float nrm = sqrtf(nsq);
        float inv = __builtin_amdgcn_rcpf(nrm + EPS_NORM);
        float e[11];
        e[0] = a2.x; e[1] = a2.y; e[2] = nrm;
#pragma unroll
        for (int i = 0; i < 8; ++i) e[3 + i] = df[i] * inv;

        int p = 11;
#pragma unroll
        for (int k = 0; k < 11; ++k) {
            acc[k] += e[k];
#pragma unroll
            for (int l = k; l < 11; ++l) { acc[p] = fmaf(e[k], e[l], acc[p]); ++p; }
        }

        int idx = atomicAdd(&cursor[d], 1);
        uint4 lo, hi;
        lo.x = pk2(e[0], e[1]); lo.y = pk2(e[2], e[3]);
        lo.z = pk2(e[4], e[5]); lo.w = pk2(e[6], e[7]);
        hi.x = pk2(e[8], e[9]); hi.y = pk2(e[10], 0.0f);
        hi.z = (unsigned)s;     hi.w = 0u;
        A16[idx] = lo;
        B16[idx] = hi;
    }

#pragma unroll
    for (int i = 0; i < 77; ++i) {
        float x = acc[i];
        for (int off = 32; off > 0; off >>= 1) x += __shfl_down(x, off);
        acc[i] = x;
    }
    __shared__ float lsum[8][77];
    int wave = threadIdx.x >> 6;
    int lane = threadIdx.x & 63;
    if (lane == 0) {
#pragma unroll
        for (int i = 0; i < 77; ++i) lsum[wave][i] = acc[i];
    }
    __syncthreads();
    if (threadIdx.x < 77) {
        float t = 0.0f;
#pragma unroll
        for (int w = 0; w < 8; ++w) t += lsum[w][threadIdx.x];
        partials[blockIdx.x * 77 + threadIdx.x] = t;
    }
}

// BN closed-form; fold scale into W' and b'.
__global__ void bn_finalize_kernel(
    const float* __restrict__ partials,
    const float* __restrict__ w0, const float* __restrict__ b0,
    const float* __restrict__ g0, const float* __restrict__ be0,
    const float* __restrict__ w1, const float* __restrict__ b1,
    const float* __restrict__ g1, const float* __restrict__ be1,
    float* __restrict__ wbp)
{
    __shared__ double gs[77];
    int t = threadIdx.x;
    if (t < 77) {
        double s = 0.0;
        for (int b = 0; b < STATS_BLOCKS; b += 4) {
            s += (double)partials[b * 77 + t] + (double)partials[(b + 1) * 77 + t]
               + (double)partials[(b + 2) * 77 + t] + (double)partials[(b + 3) * 77 + t];
        }
        gs[t] = s;
    }
    __syncthreads();
    if (t >= 128) return;
    int layer = t >> 6;
    int c = t & 63;
    const float* W  = layer ? w1 : w0;
    const float* B  = layer ? b1 : b0;
    const float* G  = layer ? g1 : g0;
    const float* BE = layer ? be1 : be0;

    const double invE = 1.0 / (double)NE;
    double m[11], wv[11];
    for (int k = 0; k < 11; ++k) {
        m[k] = gs[k] * invE;
        wv[k] = (double)W[k * 64 + c];
    }
    double md = 0.0;
    for (int k = 0; k < 11; ++k) md += m[k] * wv[k];
    double s2 = 0.0;
    int p = 11;
    for (int k = 0; k < 11; ++k)
        for (int l = k; l < 11; ++l) {
            double Me = gs[p] * invE; ++p;
            double term = Me * wv[k] * wv[l];
            s2 += (k == l) ? term : 2.0 * term;
        }
    double var = s2 - md * md;
    double mu = md + (double)B[c];
    float scale = (float)((double)G[c] / sqrt(var + (double)EPS_BN));
    float shift = (float)((double)BE[c] - mu * (double)scale);

    float* wpd = wbp + layer * 768;
    for (int k = 0; k < 11; ++k) wpd[k * 64 + c] = W[k * 64 + c] * scale;
    wpd[704 + c] = fmaf(B[c], scale, shift);
}

// Degree-bucket counting sort (DESC: heavy nodes first).
__global__ void __launch_bounds__(256) bucketA_kernel(
    const int* __restrict__ rowptr, int* __restrict__ pr, int* __restrict__ bhT)
{
    __shared__ int lh[64];
    int t = threadIdx.x, b = blockIdx.x;
    if (t < 64) lh[t] = 0;
    __syncthreads();
    int n = b * 256 + t;
    if (n < NN) {
        int d = rowptr[n + 1] - rowptr[n];
        int db = d < 63 ? d : 63;
        int bkt = 63 - db;
        int lrank = atomicAdd(&lh[bkt], 1);
        pr[n] = (lrank << 6) | bkt;
    }
    __syncthreads();
    if (t < 64) bhT[t * SCAN_BLOCKS + b] = lh[t];
}

__global__ void __launch_bounds__(256) gscanA_kernel(
    int* __restrict__ a, int* __restrict__ gbsum)
{
    int b = blockIdx.x, t = threadIdx.x;
    int i = b * 256 + t;
    int d = (i < GS_LEN) ? a[i] : 0;
    __shared__ int sh[256];
    sh[t] = d;
    __syncthreads();
    for (int off = 1; off < 256; off <<= 1) {
        int val = (t >= off) ? sh[t - off] : 0;
        __syncthreads();
        sh[t] += val;
        __syncthreads();
    }
    if (i < GS_LEN) a[i] = sh[t] - d;
    if (t == 255) gbsum[b] = sh[255];
}

__global__ void __launch_bounds__(256) gscanB_kernel(
    int* __restrict__ a, const int* __restrict__ gbsum)
{
    int b = blockIdx.x, t = threadIdx.x;
    __shared__ int sh[256];
    int s = 0;
    for (int j = t; j < b; j += 256) s += gbsum[j];
    sh[t] = s;
    __syncthreads();
    for (int off = 128; off > 0; off >>= 1) {
        if (t < off) sh[t] += sh[t + off];
        __syncthreads();
    }
    int boff = sh[0];
    int i = b * 256 + t;
    if (i < GS_LEN) a[i] += boff;
}

__global__ void __launch_bounds__(256) permB_kernel(
    const int* __restrict__ pr, const int* __restrict__ bhT,
    const int* __restrict__ rowptr, int4* __restrict__ perm4)
{
    int n = blockIdx.x * 256 + threadIdx.x;
    if (n >= NN) return;
    int p = pr[n];
    int bkt = p & 63, lrank = p >> 6, b = n >> 8;
    int pos = bhT[bkt * SCAN_BLOCKS + b] + lrank;
    perm4[pos] = make_int4(n, rowptr[n], rowptr[n + 1], 0);
}

#define FAT_BODY(LO, HI, XI)                                                 \
    do {                                                                     \
        float2 e01_ = upk2((LO).x), e23_ = upk2((LO).y);                     \
        float2 e45_ = upk2((LO).z), e67_ = upk2((LO).w);                     \
        float2 e89_ = upk2((HI).x), eAx_ = upk2((HI).y);                     \
        float e_[11] = {e01_.x, e01_.y, e23_.x, e23_.y, e45_.x, e45_.y,      \
                        e67_.x, e67_.y, e89_.x, e89_.y, eAx_.x};             \
        _Pragma("unroll")                                                    \
        for (int o = 0; o < 8; ++o) {                                        \
            float hh_ = breg[o];                                             \
            _Pragma("unroll")                                                \
            for (int k = 0; k < 11; ++k) hh_ = fmaf(e_[k], wreg[k][o], hh_); \
            msg[o] = fmaf((XI), fast_tanh(hh_), msg[o]);                     \
        }                                                                    \
    } while (0)

// Per-layer fused gather-message + mean + root + lrelu (+residual).
template<int LAYER>
__global__ void __launch_bounds__(256) layer_fat_kernel(
    const float* __restrict__ vres,
    const float* __restrict__ x,
    const uint4* __restrict__ A16, const uint4* __restrict__ B16,
    const int4* __restrict__ perm4,
    const float* __restrict__ wb,
    const float* __restrict__ rw, const float* __restrict__ rb,
    float* __restrict__ out)
{
    int g = blockIdx.x * 256 + threadIdx.x;
    int4 pm = perm4[g >> 3];
    int n = pm.x, rp0 = pm.y, rp1 = pm.z;
    int i = g & 7;

    float wreg[11][8];
#pragma unroll
    for (int k = 0; k < 11; ++k) {
        float4 wa = *(const float4*)(wb + k * 64 + i * 8);
        float4 wc = *(const float4*)(wb + k * 64 + i * 8 + 4);
        wreg[k][0] = wa.x; wreg[k][1] = wa.y; wreg[k][2] = wa.z; wreg[k][3] = wa.w;
        wreg[k][4] = wc.x; wreg[k][5] = wc.y; wreg[k][6] = wc.z; wreg[k][7] = wc.w;
    }
    float breg[8];
    {
        float4 ba = *(const float4*)(wb + 704 + i * 8);
        float4 bb = *(const float4*)(wb + 704 + i * 8 + 4);
        breg[0] = ba.x; breg[1] = ba.y; breg[2] = ba.z; breg[3] = ba.w;
        breg[4] = bb.x; breg[5] = bb.y; breg[6] = bb.z; breg[7] = bb.w;
    }

    float4 vd0 = *(const float4*)(vres + (size_t)n * 8);
    float4 vd1 = *(const float4*)(vres + (size_t)n * 8 + 4);
    float vd[8] = {vd0.x, vd0.y, vd0.z, vd0.w, vd1.x, vd1.y, vd1.z, vd1.w};

    float msg[8];
#pragma unroll
    for (int o = 0; o < 8; ++o) msg[o] = 0.0f;

    int j = rp0;
    for (; j + 2 <= rp1; j += 2) {
        uint4 lo0 = A16[j],     hi0 = B16[j];
        uint4 lo1 = A16[j + 1], hi1 = B16[j + 1];
        float xi0 = x[(size_t)(int)hi0.z * 8 + i];
        float xi1 = x[(size_t)(int)hi1.z * 8 + i];
        FAT_BODY(lo0, hi0, xi0);
        FAT_BODY(lo1, hi1, xi1);
    }
    if (j < rp1) {
        uint4 lo0 = A16[j], hi0 = B16[j];
        float xi0 = x[(size_t)(int)hi0.z * 8 + i];
        FAT_BODY(lo0, hi0, xi0);
    }

#pragma unroll
    for (int o = 0; o < 8; ++o) {
        float m = msg[o];
        m += __shfl_xor(m, 1);
        m += __shfl_xor(m, 2);
        m += __shfl_xor(m, 4);
        msg[o] = m;
    }
    float mo = msg[0];
#pragma unroll
    for (int o = 1; o < 8; ++o) if (i == o) mo = msg[o];

    float cf = (float)(rp1 - rp0);
    float invc = __builtin_amdgcn_rcpf(fmaxf(cf, 1.0f));

    float xn[8];
    if (LAYER == 0) {
#pragma unroll
        for (int q = 0; q < 8; ++q) xn[q] = vd[q];
    } else {
        float4 x0 = *(const float4*)(x + (size_t)n * 8);
        float4 x1 = *(const float4*)(x + (size_t)n * 8 + 4);
        xn[0] = x0.x; xn[1] = x0.y; xn[2] = x0.z; xn[3] = x0.w;
        xn[4] = x1.x; xn[5] = x1.y; xn[6] = x1.z; xn[7] = x1.w;
    }
    float a = fmaf(mo, invc, rb[i]);
#pragma unroll
    for (int k = 0; k < 8; ++k) a = fmaf(xn[k], rw[k * 8 + i], a);
    float y = (a > 0.0f) ? a : SLOPE * a;
    if (LAYER == 1) y += vres[(size_t)n * 8 + i];
    out[(size_t)n * 8 + i] = y;
}

extern "C" void kernel_launch(void* const* d_in, const int* in_sizes, int n_in,
                              void* d_out, int out_size, void* d_ws, size_t ws_size,
                              hipStream_t stream) {
    const float* v  = (const float*)d_in[0];
    const int* ei   = (const int*)d_in[1];
    const float* ea = (const float*)d_in[2];
    const float* en_w0  = (const float*)d_in[3];
    const float* en_b0  = (const float*)d_in[4];
    const float* en_g0  = (const float*)d_in[5];
    const float* en_be0 = (const float*)d_in[6];
    const float* rw0    = (const float*)d_in[7];
    const float* rb0    = (const float*)d_in[8];
    const float* en_w1  = (const float*)d_in[9];
    const float* en_b1  = (const float*)d_in[10];
    const float* en_g1  = (const float*)d_in[11];
    const float* en_be1 = (const float*)d_in[12];
    const float* rw1    = (const float*)d_in[13];
    const float* rb1    = (const float*)d_in[14];

    char* ws = (char*)d_ws;
    float* partials = (float*)(ws);                   // 315,392 B
    float* wbp      = (float*)(ws + 327680);          // 6,144 B
    int*   deg      = (int*)  (ws + 335872);          // 400,000 B
    int*   rowptr   = (int*)  (ws + 737280);          // 400,004 B
    int*   bsum     = (int*)  (ws + 1138688);         // 1,564 B
    int*   pr       = (int*)  (ws + 1142784);         // 400,000 B
    int4*  perm4    = (int4*) (ws + 1544192);         // 1,600,000 B
    int*   cursor   = (int*)  (ws + 3145728);         // 400,000 B
    int*   bhT      = (int*)  (ws + 3547136);         // 100,096 B
    int*   gbsum    = (int*)  (ws + 3647488);         // 392 B
    float* v1       = (float*)(ws + 3649536);         // 3,200,000 B
    uint4* A16      = (uint4*)(ws + 6850560);         // 25,600,000 B
    int*   rank     = (int*)  (ws + 6850560);         // 6.4 MB, overlays A16 (dead before expand)
    uint4* B16      = (uint4*)(ws + 32450560);        // 25,600,000 B
    unsigned long long* recs8 = (unsigned long long*)(ws + 58050560); // 12.8 MB -> end 70,850,560
    float* vout     = (float*)d_out;

    const bool newpath = (ws_size >= NEW_WS_NEEDED);

    (void)hipMemsetAsync(deg, 0, NN * sizeof(int), stream);

    if (newpath) {
        deg_rank_kernel<<<(NE + 255) / 256, 256, 0, stream>>>(ei, deg, rank);
        scanA_kernel<<<SCAN_BLOCKS, 256, 0, stream>>>(deg, rowptr, bsum);
        scanC_kernel<<<SCAN_BLOCKS, 256, 0, stream>>>(rowptr, bsum, cursor);
        bucketA_kernel<<<SCAN_BLOCKS, 256, 0, stream>>>(rowptr, pr, bhT);
        gscanA_kernel<<<GS_BLOCKS, 256, 0, stream>>>(bhT, gbsum);
        gscanB_kernel<<<GS_BLOCKS, 256, 0, stream>>>(bhT, gbsum);
        permB_kernel<<<SCAN_BLOCKS, 256, 0, stream>>>(pr, bhT, rowptr, perm4);
        thin_scatter_kernel<<<(NE + 255) / 256, 256, 0, stream>>>(ei, ea, rowptr, rank, recs8);
        expand_stats_kernel<<<EXP_BLOCKS, 256, 0, stream>>>(v, recs8, A16, B16, partials);
    } else {
        deg_kernel<<<(NE / 4 + 255) / 256, 256, 0, stream>>>(ei, deg);
        scanA_kernel<<<SCAN_BLOCKS, 256, 0, stream>>>(deg, rowptr, bsum);
        scanC_kernel<<<SCAN_BLOCKS, 256, 0, stream>>>(rowptr, bsum, cursor);
        scatstat_kernel<<<STATS_BLOCKS, STATS_THREADS, 0, stream>>>(v, ei, ea, cursor, A16, B16, partials);
        bucketA_kernel<<<SCAN_BLOCKS, 256, 0, stream>>>(rowptr, pr, bhT);
        gscanA_kernel<<<GS_BLOCKS, 256, 0, stream>>>(bhT, gbsum);
        gscanB_kernel<<<GS_BLOCKS, 256, 0, stream>>>(bhT, gbsum);
        permB_kernel<<<SCAN_BLOCKS, 256, 0, stream>>>(pr, bhT, rowptr, perm4);
    }
    bn_finalize_kernel<<<1, 128, 0, stream>>>(partials, en_w0, en_b0, en_g0, en_be0,
                                              en_w1, en_b1, en_g1, en_be1, wbp);

    const int LB = (NN * 8) / 256;   // 3125, exact
    layer_fat_kernel<0><<<LB, 256, 0, stream>>>(v, v,  A16, B16, perm4, wbp,       rw0, rb0, v1);
    layer_fat_kernel<1><<<LB, 256, 0, stream>>>(v, v1, A16, B16, perm4, wbp + 768, rw1, rb1, vout);
}

// Round 13
// 288.728 us; speedup vs baseline: 1.5795x; 1.2657x over previous
//
#include <hip/hip_runtime.h>
#include <hip/hip_fp16.h>
#include <math.h>

#define NN 100000
#define NE 1600000
#define EPS_BN 1e-5f
#define EPS_NORM 1e-12f
#define SLOPE 0.01f
#define PART_BLOCKS 1024
#define EXP_BLOCKS 1024
#define SCAN_BLOCKS ((NN + 255) / 256)       // 391
#define GS_LEN (64 * SCAN_BLOCKS)            // 25024
#define GS_BLOCKS ((GS_LEN + 255) / 256)     // 98

typedef _Float16 h2 __attribute__((ext_vector_type(2)));

__device__ __forceinline__ float fast_tanh(float x) {
    float t = exp2f(x * 2.885390082f);
    return fmaf(-2.0f, __builtin_amdgcn_rcpf(t + 1.0f), 1.0f);
}

__device__ __forceinline__ unsigned pk2(float a, float b) {
    union { __half2 h; unsigned u; } c;
    c.h = __float22half2_rn(make_float2(a, b));
    return c.u;
}

__device__ __forceinline__ h2 u2h(unsigned x) {
    union { unsigned u; h2 h; } c; c.u = x; return c.h;
}

#if __has_builtin(__builtin_amdgcn_fdot2)
#define FDOT2(A, B, C) __builtin_amdgcn_fdot2((A), (B), (C), false)
#else
__device__ __forceinline__ float FDOT2(h2 a, h2 b, float c) {
    return fmaf((float)a.x, (float)b.x, fmaf((float)a.y, (float)b.y, c));
}
#endif

// Pass 0: in-degree + stable rank per edge.
__global__ void __launch_bounds__(256) deg_rank_kernel(
    const int* __restrict__ ei, int* __restrict__ deg, int* __restrict__ rank)
{
    int e = blockIdx.x * 256 + threadIdx.x;
    if (e >= NE) return;
    int d = ei[NE + e];
    rank[e] = atomicAdd(&deg[d], 1);
}

// Pass 1a: per-block exclusive scan of deg -> rowptr + block sums.
__global__ void __launch_bounds__(256) scanA_kernel(
    const int* __restrict__ deg, int* __restrict__ rowptr, int* __restrict__ bsum)
{
    int b = blockIdx.x, t = threadIdx.x;
    int i = b * 256 + t;
    int d = (i < NN) ? deg[i] : 0;
    __shared__ int sh[256];
    sh[t] = d;
    __syncthreads();
    for (int off = 1; off < 256; off <<= 1) {
        int val = (t >= off) ? sh[t - off] : 0;
        __syncthreads();
        sh[t] += val;
        __syncthreads();
    }
    if (i < NN) rowptr[i] = sh[t] - d;
    if (t == 255) bsum[b] = sh[255];
}

// Pass 1b: add block offsets in-place.
__global__ void __launch_bounds__(256) scanC_kernel(
    int* __restrict__ rowptr, const int* __restrict__ bsum)
{
    int b = blockIdx.x, t = threadIdx.x;
    __shared__ int sh[256];
    int s = 0;
    for (int j = t; j < b; j += 256) s += bsum[j];
    sh[t] = s;
    __syncthreads();
    for (int off = 128; off > 0; off >>= 1) {
        if (t < off) sh[t] += sh[t + off];
        __syncthreads();
    }
    int boff = sh[0];
    int i = b * 256 + t;
    if (i < NN) rowptr[i] += boff;
    if (b == 0 && t == 0) rowptr[NN] = NE;
}

// Pass 2: scatter 8B packed record [dst:17|src:17|a0:15|a1:15]; no atomics.
__global__ void __launch_bounds__(256) thin_scatter_kernel(
    const int* __restrict__ ei, const float* __restrict__ ea,
    const int* __restrict__ rowptr, const int* __restrict__ rank,
    unsigned long long* __restrict__ recs8)
{
    int e = blockIdx.x * 256 + threadIdx.x;
    if (e >= NE) return;
    int s = ei[e];
    int d = ei[NE + e];
    float2 a2 = *(const float2*)(ea + 2 * (size_t)e);
    unsigned a0q = __float2uint_rn(a2.x * 32768.0f); if (a0q > 32767u) a0q = 32767u;
    unsigned a1q = __float2uint_rn(a2.y * 32768.0f); if (a1q > 32767u) a1q = 32767u;
    int pos = rowptr[d] + rank[e];
    unsigned long long rec = ((unsigned long long)(unsigned)d << 47)
                           | ((unsigned long long)(unsigned)s << 30)
                           | ((unsigned long long)a0q << 15)
                           | (unsigned long long)a1q;
    recs8[pos] = rec;
}

// Pass 3: edge-parallel expand thin->fat + fused moments, LANE-PAIR split:
// pair (even,odd) shares one edge; even keeps moments 0..38, odd 39..76.
// No 77-register accumulator -> no scratch spill. Coalesced fat writes.
__global__ void __launch_bounds__(256, 4) expand_stats_kernel(
    const float* __restrict__ v,
    const unsigned long long* __restrict__ recs8,
    uint4* __restrict__ A16, uint4* __restrict__ B16,
    float* __restrict__ partials)   // [EXP_BLOCKS][77]
{
    float acc[39];
#pragma unroll
    for (int i = 0; i < 39; ++i) acc[i] = 0.0f;

    int tid = blockIdx.x * 256 + threadIdx.x;
    int hi = tid & 1;
    for (int eidx = tid >> 1; eidx < NE; eidx += (EXP_BLOCKS * 256) / 2) {
        unsigned long long r = recs8[eidx];
        int d = (int)(r >> 47);
        int s = (int)((r >> 30) & 0x1FFFFu);
        float a0 = (float)(unsigned)((r >> 15) & 0x7FFFu) * (1.0f / 32768.0f);
        float a1 = (float)(unsigned)(r & 0x7FFFu) * (1.0f / 32768.0f);

        float4 s0 = *(const float4*)(v + (size_t)s * 8);
        float4 s1 = *(const float4*)(v + (size_t)s * 8 + 4);
        float4 d0 = *(const float4*)(v + (size_t)d * 8);
        float4 d1 = *(const float4*)(v + (size_t)d * 8 + 4);
        float df[8];
        df[0] = d0.x - s0.x; df[1] = d0.y - s0.y;
        df[2] = d0.z - s0.z; df[3] = d0.w - s0.w;
        df[4] = d1.x - s1.x; df[5] = d1.y - s1.y;
        df[6] = d1.z - s1.z; df[7] = d1.w - s1.w;
        float nsq = 0.0f;
#pragma unroll
        for (int q = 0; q < 8; ++q) nsq = fmaf(df[q], df[q], nsq);
        float nrm = sqrtf(nsq);
        float inv = __builtin_amdgcn_rcpf(nrm + EPS_NORM);
        float e[11];
        e[0] = a0; e[1] = a1; e[2] = nrm;
#pragma unroll
        for (int q = 0; q < 8; ++q) e[3 + q] = df[q] * inv;

        if (!hi) {
#pragma unroll
            for (int k = 0; k < 11; ++k) acc[k] += e[k];
            int p = 11;
#pragma unroll
            for (int k = 0; k < 11; ++k)
#pragma unroll
                for (int l = k; l < 11; ++l) {
                    if (p < 39) acc[p] = fmaf(e[k], e[l], acc[p]);
                    ++p;
                }
            uint4 lo;
            lo.x = pk2(e[0], e[1]); lo.y = pk2(e[2], e[3]);
            lo.z = pk2(e[4], e[5]); lo.w = pk2(e[6], e[7]);
            A16[eidx] = lo;
        } else {
            int p = 11;
#pragma unroll
            for (int k = 0; k < 11; ++k)
#pragma unroll
                for (int l = k; l < 11; ++l) {
                    if (p >= 39) acc[p - 39] = fmaf(e[k], e[l], acc[p - 39]);
                    ++p;
                }
            uint4 hv;
            hv.x = pk2(e[8], e[9]); hv.y = pk2(e[10], 0.0f);
            hv.z = (unsigned)s;     hv.w = 0u;
            B16[eidx] = hv;
        }
    }

    // parity-preserving butterfly: lane0 sums even lanes, lane1 sums odd.
#pragma unroll
    for (int i = 0; i < 39; ++i) {
        float x = acc[i];
        x += __shfl_down(x, 2);
        x += __shfl_down(x, 4);
        x += __shfl_down(x, 8);
        x += __shfl_down(x, 16);
        x += __shfl_down(x, 32);
        acc[i] = x;
    }
    __shared__ float lsum[4][77];
    int wave = threadIdx.x >> 6;
    int lane = threadIdx.x & 63;
    if (lane == 0) {
#pragma unroll
        for (int i = 0; i < 39; ++i) lsum[wave][i] = acc[i];
    }
    if (lane == 1) {
#pragma unroll
        for (int i = 0; i < 38; ++i) lsum[wave][39 + i] = acc[i];
    }
    __syncthreads();
    if (threadIdx.x < 77) {
        float t = lsum[0][threadIdx.x] + lsum[1][threadIdx.x]
                + lsum[2][threadIdx.x] + lsum[3][threadIdx.x];
        partials[blockIdx.x * 77 + threadIdx.x] = t;
    }
}

// BN closed-form; fold scale into W'/b'; ALSO emit f16-pair packed weights.
__global__ void bn_finalize_kernel(
    const float* __restrict__ partials,
    const float* __restrict__ w0, const float* __restrict__ b0,
    const float* __restrict__ g0, const float* __restrict__ be0,
    const float* __restrict__ w1, const float* __restrict__ b1,
    const float* __restrict__ g1, const float* __restrict__ be1,
    float* __restrict__ wbp)   // layer l at +l*1152: W'[704], b'[64], pk[384]
{
    __shared__ double gs[77];
    int t = threadIdx.x;
    if (t < 77) {
        double s = 0.0;
        for (int b = 0; b < PART_BLOCKS; b += 4) {
            s += (double)partials[b * 77 + t] + (double)partials[(b + 1) * 77 + t]
               + (double)partials[(b + 2) * 77 + t] + (double)partials[(b + 3) * 77 + t];
        }
        gs[t] = s;
    }
    __syncthreads();
    if (t >= 128) return;
    int layer = t >> 6;
    int c = t & 63;
    const float* W  = layer ? w1 : w0;
    const float* B  = layer ? b1 : b0;
    const float* G  = layer ? g1 : g0;
    const float* BE = layer ? be1 : be0;

    const double invE = 1.0 / (double)NE;
    double m[11], wv[11];
    for (int k = 0; k < 11; ++k) {
        m[k] = gs[k] * invE;
        wv[k] = (double)W[k * 64 + c];
    }
    double md = 0.0;
    for (int k = 0; k < 11; ++k) md += m[k] * wv[k];
    double s2 = 0.0;
    int p = 11;
    for (int k = 0; k < 11; ++k)
        for (int l = k; l < 11; ++l) {
            double Me = gs[p] * invE; ++p;
            double term = Me * wv[k] * wv[l];
            s2 += (k == l) ? term : 2.0 * term;
        }
    double var = s2 - md * md;
    double mu = md + (double)B[c];
    float scale = (float)((double)G[c] / sqrt(var + (double)EPS_BN));
    float shift = (float)((double)BE[c] - mu * (double)scale);

    float* wpd = wbp + layer * 1152;
    for (int k = 0; k < 11; ++k) wpd[k * 64 + c] = W[k * 64 + c] * scale;
    wpd[704 + c] = fmaf(B[c], scale, shift);
    unsigned* pw = (unsigned*)(wpd + 768);
    for (int kp = 0; kp < 6; ++kp) {
        float wlo = W[(2 * kp) * 64 + c] * scale;
        float whi = (2 * kp + 1 < 11) ? W[(2 * kp + 1) * 64 + c] * scale : 0.0f;
        pw[kp * 64 + c] = pk2(wlo, whi);
    }
}

// Degree-bucket counting sort (DESC: heavy nodes first).
__global__ void __launch_bounds__(256) bucketA_kernel(
    const int* __restrict__ rowptr, int* __restrict__ pr, int* __restrict__ bhT)
{
    __shared__ int lh[64];
    int t = threadIdx.x, b = blockIdx.x;
    if (t < 64) lh[t] = 0;
    __syncthreads();
    int n = b * 256 + t;
    if (n < NN) {
        int d = rowptr[n + 1] - rowptr[n];
        int db = d < 63 ? d : 63;
        int bkt = 63 - db;
        int lrank = atomicAdd(&lh[bkt], 1);
        pr[n] = (lrank << 6) | bkt;
    }
    __syncthreads();
    if (t < 64) bhT[t * SCAN_BLOCKS + b] = lh[t];
}

__global__ void __launch_bounds__(256) gscanA_kernel(
    int* __restrict__ a, int* __restrict__ gbsum)
{
    int b = blockIdx.x, t = threadIdx.x;
    int i = b * 256 + t;
    int d = (i < GS_LEN) ? a[i] : 0;
    __shared__ int sh[256];
    sh[t] = d;
    __syncthreads();
    for (int off = 1; off < 256; off <<= 1) {
        int val = (t >= off) ? sh[t - off] : 0;
        __syncthreads();
        sh[t] += val;
        __syncthreads();
    }
    if (i < GS_LEN) a[i] = sh[t] - d;
    if (t == 255) gbsum[b] = sh[255];
}

__global__ void __launch_bounds__(256) gscanB_kernel(
    int* __restrict__ a, const int* __restrict__ gbsum)
{
    int b = blockIdx.x, t = threadIdx.x;
    __shared__ int sh[256];
    int s = 0;
    for (int j = t; j < b; j += 256) s += gbsum[j];
    sh[t] = s;
    __syncthreads();
    for (int off = 128; off > 0; off >>= 1) {
        if (t < off) sh[t] += sh[t + off];
        __syncthreads();
    }
    int boff = sh[0];
    int i = b * 256 + t;
    if (i < GS_LEN) a[i] += boff;
}

__global__ void __launch_bounds__(256) permB_kernel(
    const int* __restrict__ pr, const int* __restrict__ bhT,
    const int* __restrict__ rowptr, int4* __restrict__ perm4)
{
    int n = blockIdx.x * 256 + threadIdx.x;
    if (n >= NN) return;
    int p = pr[n];
    int bkt = p & 63, lrank = p >> 6, b = n >> 8;
    int pos = bhT[bkt * SCAN_BLOCKS + b] + lrank;
    perm4[pos] = make_int4(n, rowptr[n], rowptr[n + 1], 0);
}

// dot2 edge body: e-pairs straight from the fat record, packed f16 weights.
#define FAT_BODY2(LO, HI, XI)                                                \
    do {                                                                     \
        h2 ep0 = u2h((LO).x), ep1 = u2h((LO).y);                             \
        h2 ep2 = u2h((LO).z), ep3 = u2h((LO).w);                             \
        h2 ep4 = u2h((HI).x), ep5 = u2h((HI).y);                             \
        _Pragma("unroll")                                                    \
        for (int o = 0; o < 8; ++o) {                                        \
            float hh = breg[o];                                              \
            hh = FDOT2(ep0, pw[0][o], hh);                                   \
            hh = FDOT2(ep1, pw[1][o], hh);                                   \
            hh = FDOT2(ep2, pw[2][o], hh);                                   \
            hh = FDOT2(ep3, pw[3][o], hh);                                   \
            hh = FDOT2(ep4, pw[4][o], hh);                                   \
            hh = FDOT2(ep5, pw[5][o], hh);                                   \
            msg[o] = fmaf((XI), fast_tanh(hh), msg[o]);                      \
        }                                                                    \
    } while (0)

// Per-layer fused gather-message + mean + root + lrelu (+residual).
template<int LAYER>
__global__ void __launch_bounds__(256, 4) layer_fat_kernel(
    const float* __restrict__ vres,
    const float* __restrict__ x,
    const uint4* __restrict__ A16, const uint4* __restrict__ B16,
    const int4* __restrict__ perm4,
    const float* __restrict__ wb,   // layer base: W'f32[704], b'[64], pk[384]
    const float* __restrict__ rw, const float* __restrict__ rb,
    float* __restrict__ out)
{
    int g = blockIdx.x * 256 + threadIdx.x;
    int4 pm = perm4[g >> 3];
    int n = pm.x, rp0 = pm.y, rp1 = pm.z;
    int i = g & 7;

    h2 pw[6][8];
    const unsigned* pwg = (const unsigned*)(wb + 768);
#pragma unroll
    for (int kp = 0; kp < 6; ++kp) {
        uint4 pa = *(const uint4*)(pwg + kp * 64 + i * 8);
        uint4 pb = *(const uint4*)(pwg + kp * 64 + i * 8 + 4);
        pw[kp][0] = u2h(pa.x); pw[kp][1] = u2h(pa.y);
        pw[kp][2] = u2h(pa.z); pw[kp][3] = u2h(pa.w);
        pw[kp][4] = u2h(pb.x); pw[kp][5] = u2h(pb.y);
        pw[kp][6] = u2h(pb.z); pw[kp][7] = u2h(pb.w);
    }
    float breg[8];
    {
        float4 ba = *(const float4*)(wb + 704 + i * 8);
        float4 bb = *(const float4*)(wb + 704 + i * 8 + 4);
        breg[0] = ba.x; breg[1] = ba.y; breg[2] = ba.z; breg[3] = ba.w;
        breg[4] = bb.x; breg[5] = bb.y; breg[6] = bb.z; breg[7] = bb.w;
    }

    float4 vd0 = *(const float4*)(vres + (size_t)n * 8);
    float4 vd1 = *(const float4*)(vres + (size_t)n * 8 + 4);
    float vd[8] = {vd0.x, vd0.y, vd0.z, vd0.w, vd1.x, vd1.y, vd1.z, vd1.w};

    float msg[8];
#pragma unroll
    for (int o = 0; o < 8; ++o) msg[o] = 0.0f;

    int j = rp0;
    for (; j + 2 <= rp1; j += 2) {
        uint4 lo0 = A16[j],     hi0 = B16[j];
        uint4 lo1 = A16[j + 1], hi1 = B16[j + 1];
        float xi0 = x[(size_t)(int)hi0.z * 8 + i];
        float xi1 = x[(size_t)(int)hi1.z * 8 + i];
        FAT_BODY2(lo0, hi0, xi0);
        FAT_BODY2(lo1, hi1, xi1);
    }
    if (j < rp1) {
        uint4 lo0 = A16[j], hi0 = B16[j];
        float xi0 = x[(size_t)(int)hi0.z * 8 + i];
        FAT_BODY2(lo0, hi0, xi0);
    }

#pragma unroll
    for (int o = 0; o < 8; ++o) {
        float m = msg[o];
        m += __shfl_xor(m, 1);
        m += __shfl_xor(m, 2);
        m += __shfl_xor(m, 4);
        msg[o] = m;
    }
    float mo = msg[0];
#pragma unroll
    for (int o = 1; o < 8; ++o) if (i == o) mo = msg[o];

    float cf = (float)(rp1 - rp0);
    float invc = __builtin_amdgcn_rcpf(fmaxf(cf, 1.0f));

    float xn[8];
    if (LAYER == 0) {
#pragma unroll
        for (int q = 0; q < 8; ++q) xn[q] = vd[q];
    } else {
        float4 x0 = *(const float4*)(x + (size_t)n * 8);
        float4 x1 = *(const float4*)(x + (size_t)n * 8 + 4);
        xn[0] = x0.x; xn[1] = x0.y; xn[2] = x0.z; xn[3] = x0.w;
        xn[4] = x1.x; xn[5] = x1.y; xn[6] = x1.z; xn[7] = x1.w;
    }
    float a = fmaf(mo, invc, rb[i]);
#pragma unroll
    for (int k = 0; k < 8; ++k) a = fmaf(xn[k], rw[k * 8 + i], a);
    float y = (a > 0.0f) ? a : SLOPE * a;
    if (LAYER == 1) y += vres[(size_t)n * 8 + i];
    out[(size_t)n * 8 + i] = y;
}

extern "C" void kernel_launch(void* const* d_in, const int* in_sizes, int n_in,
                              void* d_out, int out_size, void* d_ws, size_t ws_size,
                              hipStream_t stream) {
    const float* v  = (const float*)d_in[0];
    const int* ei   = (const int*)d_in[1];
    const float* ea = (const float*)d_in[2];
    const float* en_w0  = (const float*)d_in[3];
    const float* en_b0  = (const float*)d_in[4];
    const float* en_g0  = (const float*)d_in[5];
    const float* en_be0 = (const float*)d_in[6];
    const float* rw0    = (const float*)d_in[7];
    const float* rb0    = (const float*)d_in[8];
    const float* en_w1  = (const float*)d_in[9];
    const float* en_b1  = (const float*)d_in[10];
    const float* en_g1  = (const float*)d_in[11];
    const float* en_be1 = (const float*)d_in[12];
    const float* rw1    = (const float*)d_in[13];
    const float* rb1    = (const float*)d_in[14];

    char* ws = (char*)d_ws;
    float* partials = (float*)(ws);                   // 1024*77*4 = 315,392 B
    float* wbp      = (float*)(ws + 327680);          // 2*1152*4 = 9,216 B
    int*   deg      = (int*)  (ws + 340992);          // 400,000 B
    int*   rowptr   = (int*)  (ws + 741376);          // 400,004 B
    int*   bsum     = (int*)  (ws + 1141760);         // 1,564 B
    int*   pr       = (int*)  (ws + 1145856);         // 400,000 B
    int4*  perm4    = (int4*) (ws + 1546240);         // 1,600,000 B
    int*   bhT      = (int*)  (ws + 3547136);         // 100,096 B
    int*   gbsum    = (int*)  (ws + 3647488);         // 392 B
    float* v1       = (float*)(ws + 3649536);         // 3,200,000 B
    uint4* A16      = (uint4*)(ws + 6850560);         // 25,600,000 B
    int*   rank     = (int*)  (ws + 6850560);         // 6.4 MB, overlays A16 (dead before expand)
    uint4* B16      = (uint4*)(ws + 32450560);        // 25,600,000 B
    unsigned long long* recs8 = (unsigned long long*)(ws + 58050560); // 12.8 MB -> 70,850,560
    float* vout     = (float*)d_out;

    (void)hipMemsetAsync(deg, 0, NN * sizeof(int), stream);

    deg_rank_kernel<<<(NE + 255) / 256, 256, 0, stream>>>(ei, deg, rank);
    scanA_kernel<<<SCAN_BLOCKS, 256, 0, stream>>>(deg, rowptr, bsum);
    scanC_kernel<<<SCAN_BLOCKS, 256, 0, stream>>>(rowptr, bsum);
    bucketA_kernel<<<SCAN_BLOCKS, 256, 0, stream>>>(rowptr, pr, bhT);
    gscanA_kernel<<<GS_BLOCKS, 256, 0, stream>>>(bhT, gbsum);
    gscanB_kernel<<<GS_BLOCKS, 256, 0, stream>>>(bhT, gbsum);
    permB_kernel<<<SCAN_BLOCKS, 256, 0, stream>>>(pr, bhT, rowptr, perm4);
    thin_scatter_kernel<<<(NE + 255) / 256, 256, 0, stream>>>(ei, ea, rowptr, rank, recs8);
    expand_stats_kernel<<<EXP_BLOCKS, 256, 0, stream>>>(v, recs8, A16, B16, partials);
    bn_finalize_kernel<<<1, 128, 0, stream>>>(partials, en_w0, en_b0, en_g0, en_be0,
                                              en_w1, en_b1, en_g1, en_be1, wbp);

    const int LB = (NN * 8) / 256;   // 3125, exact
    layer_fat_kernel<0><<<LB, 256, 0, stream>>>(v, v,  A16, B16, perm4, wbp,        rw0, rb0, v1);
    layer_fat_kernel<1><<<LB, 256, 0, stream>>>(v, v1, A16, B16, perm4, wbp + 1152, rw1, rb1, vout);
}

// Round 14
// 261.819 us; speedup vs baseline: 1.7419x; 1.1028x over previous
//
#include <hip/hip_runtime.h>
#include <hip/hip_fp16.h>
#include <math.h>

#define NN 100000
#define NE 1600000
#define EPS_BN 1e-5f
#define EPS_NORM 1e-12f
#define SLOPE 0.01f
#define PART_BLOCKS 1024
#define EXP_BLOCKS 1024
#define SCAN_BLOCKS ((NN + 255) / 256)       // 391
#define GS_LEN (64 * SCAN_BLOCKS)            // 25024
#define GS_BLOCKS ((GS_LEN + 255) / 256)     // 98

typedef _Float16 h2 __attribute__((ext_vector_type(2)));

#if __has_builtin(__builtin_amdgcn_exp2f)
#define EXP2F(x) __builtin_amdgcn_exp2f(x)
#else
#define EXP2F(x) exp2f(x)
#endif

__device__ __forceinline__ float fast_tanh(float x) {
    float t = EXP2F(x * 2.885390082f);
    return fmaf(-2.0f, __builtin_amdgcn_rcpf(t + 1.0f), 1.0f);
}

__device__ __forceinline__ unsigned pk2(float a, float b) {
    union { __half2 h; unsigned u; } c;
    c.h = __float22half2_rn(make_float2(a, b));
    return c.u;
}

__device__ __forceinline__ h2 u2h(unsigned x) {
    union { unsigned u; h2 h; } c; c.u = x; return c.h;
}

#if __has_builtin(__builtin_amdgcn_fdot2)
#define FDOT2(A, B, C) __builtin_amdgcn_fdot2((A), (B), (C), false)
#else
__device__ __forceinline__ float FDOT2(h2 a, h2 b, float c) {
    return fmaf((float)a.x, (float)b.x, fmaf((float)a.y, (float)b.y, c));
}
#endif

// Pass 0: in-degree + stable rank per edge.
__global__ void __launch_bounds__(256) deg_rank_kernel(
    const int* __restrict__ ei, int* __restrict__ deg, int* __restrict__ rank)
{
    int e = blockIdx.x * 256 + threadIdx.x;
    if (e >= NE) return;
    int d = ei[NE + e];
    rank[e] = atomicAdd(&deg[d], 1);
}

// Pass 1a: per-block scan of deg -> block-local rowptr + bsum. FUSED:
// degree-bucket hist (LDS) + per-node bucket rank (pr) + bhT matrix.
__global__ void __launch_bounds__(256) scanA_kernel(
    const int* __restrict__ deg, int* __restrict__ rowptr, int* __restrict__ bsum,
    int* __restrict__ pr, int* __restrict__ bhT)
{
    int b = blockIdx.x, t = threadIdx.x;
    int i = b * 256 + t;
    int d = (i < NN) ? deg[i] : 0;
    __shared__ int sh[256];
    __shared__ int lh[64];
    if (t < 64) lh[t] = 0;
    sh[t] = d;
    __syncthreads();
    for (int off = 1; off < 256; off <<= 1) {
        int val = (t >= off) ? sh[t - off] : 0;
        __syncthreads();
        sh[t] += val;
        __syncthreads();
    }
    if (i < NN) {
        rowptr[i] = sh[t] - d;     // exclusive within block
        int db = d < 63 ? d : 63;
        int bkt = 63 - db;         // descending degree order (LPT)
        int lrank = atomicAdd(&lh[bkt], 1);
        pr[i] = (lrank << 6) | bkt;
    }
    if (t == 255) bsum[b] = sh[255];
    __syncthreads();
    if (t < 64) bhT[t * SCAN_BLOCKS + b] = lh[t];   // bucket-major
}

// Pass 1b: add block offsets in-place.
__global__ void __launch_bounds__(256) scanC_kernel(
    int* __restrict__ rowptr, const int* __restrict__ bsum)
{
    int b = blockIdx.x, t = threadIdx.x;
    __shared__ int sh[256];
    int s = 0;
    for (int j = t; j < b; j += 256) s += bsum[j];
    sh[t] = s;
    __syncthreads();
    for (int off = 128; off > 0; off >>= 1) {
        if (t < off) sh[t] += sh[t + off];
        __syncthreads();
    }
    int boff = sh[0];
    int i = b * 256 + t;
    if (i < NN) rowptr[i] += boff;
    if (b == 0 && t == 0) rowptr[NN] = NE;
}

// Pass 2: scatter 8B packed record [dst:17|src:17|a0:15|a1:15]; no atomics.
__global__ void __launch_bounds__(256) thin_scatter_kernel(
    const int* __restrict__ ei, const float* __restrict__ ea,
    const int* __restrict__ rowptr, const int* __restrict__ rank,
    unsigned long long* __restrict__ recs8)
{
    int e = blockIdx.x * 256 + threadIdx.x;
    if (e >= NE) return;
    int s = ei[e];
    int d = ei[NE + e];
    float2 a2 = *(const float2*)(ea + 2 * (size_t)e);
    unsigned a0q = __float2uint_rn(a2.x * 32768.0f); if (a0q > 32767u) a0q = 32767u;
    unsigned a1q = __float2uint_rn(a2.y * 32768.0f); if (a1q > 32767u) a1q = 32767u;
    int pos = rowptr[d] + rank[e];
    unsigned long long rec = ((unsigned long long)(unsigned)d << 47)
                           | ((unsigned long long)(unsigned)s << 30)
                           | ((unsigned long long)a0q << 15)
                           | (unsigned long long)a1q;
    recs8[pos] = rec;
}

// Pass 3: edge-parallel expand thin->fat + fused moments, lane-pair split.
__global__ void __launch_bounds__(256, 4) expand_stats_kernel(
    const float* __restrict__ v,
    const unsigned long long* __restrict__ recs8,
    uint4* __restrict__ A16, uint4* __restrict__ B16,
    float* __restrict__ partials)   // [EXP_BLOCKS][77]
{
    float acc[39];
#pragma unroll
    for (int i = 0; i < 39; ++i) acc[i] = 0.0f;

    int tid = blockIdx.x * 256 + threadIdx.x;
    int hi = tid & 1;
    for (int eidx = tid >> 1; eidx < NE; eidx += (EXP_BLOCKS * 256) / 2) {
        unsigned long long r = recs8[eidx];
        int d = (int)(r >> 47);
        int s = (int)((r >> 30) & 0x1FFFFu);
        float a0 = (float)(unsigned)((r >> 15) & 0x7FFFu) * (1.0f / 32768.0f);
        float a1 = (float)(unsigned)(r & 0x7FFFu) * (1.0f / 32768.0f);

        float4 s0 = *(const float4*)(v + (size_t)s * 8);
        float4 s1 = *(const float4*)(v + (size_t)s * 8 + 4);
        float4 d0 = *(const float4*)(v + (size_t)d * 8);
        float4 d1 = *(const float4*)(v + (size_t)d * 8 + 4);
        float df[8];
        df[0] = d0.x - s0.x; df[1] = d0.y - s0.y;
        df[2] = d0.z - s0.z; df[3] = d0.w - s0.w;
        df[4] = d1.x - s1.x; df[5] = d1.y - s1.y;
        df[6] = d1.z - s1.z; df[7] = d1.w - s1.w;
        float nsq = 0.0f;
#pragma unroll
        for (int q = 0; q < 8; ++q) nsq = fmaf(df[q], df[q], nsq);
        float nrm = sqrtf(nsq);
        float inv = __builtin_amdgcn_rcpf(nrm + EPS_NORM);
        float e[11];
        e[0] = a0; e[1] = a1; e[2] = nrm;
#pragma unroll
        for (int q = 0; q < 8; ++q) e[3 + q] = df[q] * inv;

        if (!hi) {
#pragma unroll
            for (int k = 0; k < 11; ++k) acc[k] += e[k];
            int p = 11;
#pragma unroll
            for (int k = 0; k < 11; ++k)
#pragma unroll
                for (int l = k; l < 11; ++l) {
                    if (p < 39) acc[p] = fmaf(e[k], e[l], acc[p]);
                    ++p;
                }
            uint4 lo;
            lo.x = pk2(e[0], e[1]); lo.y = pk2(e[2], e[3]);
            lo.z = pk2(e[4], e[5]); lo.w = pk2(e[6], e[7]);
            A16[eidx] = lo;
        } else {
            int p = 11;
#pragma unroll
            for (int k = 0; k < 11; ++k)
#pragma unroll
                for (int l = k; l < 11; ++l) {
                    if (p >= 39) acc[p - 39] = fmaf(e[k], e[l], acc[p - 39]);
                    ++p;
                }
            uint4 hv;
            hv.x = pk2(e[8], e[9]); hv.y = pk2(e[10], 0.0f);
            hv.z = (unsigned)s;     hv.w = 0u;
            B16[eidx] = hv;
        }
    }

    // parity-preserving butterfly: lane0 sums even lanes, lane1 sums odd.
#pragma unroll
    for (int i = 0; i < 39; ++i) {
        float x = acc[i];
        x += __shfl_down(x, 2);
        x += __shfl_down(x, 4);
        x += __shfl_down(x, 8);
        x += __shfl_down(x, 16);
        x += __shfl_down(x, 32);
        acc[i] = x;
    }
    __shared__ float lsum[4][77];
    int wave = threadIdx.x >> 6;
    int lane = threadIdx.x & 63;
    if (lane == 0) {
#pragma unroll
        for (int i = 0; i < 39; ++i) lsum[wave][i] = acc[i];
    }
    if (lane == 1) {
#pragma unroll
        for (int i = 0; i < 38; ++i) lsum[wave][39 + i] = acc[i];
    }
    __syncthreads();
    if (threadIdx.x < 77) {
        float t = lsum[0][threadIdx.x] + lsum[1][threadIdx.x]
                + lsum[2][threadIdx.x] + lsum[3][threadIdx.x];
        partials[blockIdx.x * 77 + threadIdx.x] = t;
    }
}

// BN closed-form; fold scale into W'/b'; emit f16-pair packed weights.
__global__ void bn_finalize_kernel(
    const float* __restrict__ partials,
    const float* __restrict__ w0, const float* __restrict__ b0,
    const float* __restrict__ g0, const float* __restrict__ be0,
    const float* __restrict__ w1, const float* __restrict__ b1,
    const float* __restrict__ g1, const float* __restrict__ be1,
    float* __restrict__ wbp)   // layer l at +l*1152: W'[704], b'[64], pk[384]
{
    __shared__ double gs[77];
    int t = threadIdx.x;
    if (t < 77) {
        double s = 0.0;
        for (int b = 0; b < PART_BLOCKS; b += 4) {
            s += (double)partials[b * 77 + t] + (double)partials[(b + 1) * 77 + t]
               + (double)partials[(b + 2) * 77 + t] + (double)partials[(b + 3) * 77 + t];
        }
        gs[t] = s;
    }
    __syncthreads();
    if (t >= 128) return;
    int layer = t >> 6;
    int c = t & 63;
    const float* W  = layer ? w1 : w0;
    const float* B  = layer ? b1 : b0;
    const float* G  = layer ? g1 : g0;
    const float* BE = layer ? be1 : be0;

    const double invE = 1.0 / (double)NE;
    double m[11], wv[11];
    for (int k = 0; k < 11; ++k) {
        m[k] = gs[k] * invE;
        wv[k] = (double)W[k * 64 + c];
    }
    double md = 0.0;
    for (int k = 0; k < 11; ++k) md += m[k] * wv[k];
    double s2 = 0.0;
    int p = 11;
    for (int k = 0; k < 11; ++k)
        for (int l = k; l < 11; ++l) {
            double Me = gs[p] * invE; ++p;
            double term = Me * wv[k] * wv[l];
            s2 += (k == l) ? term : 2.0 * term;
        }
    double var = s2 - md * md;
    double mu = md + (double)B[c];
    float scale = (float)((double)G[c] / sqrt(var + (double)EPS_BN));
    float shift = (float)((double)BE[c] - mu * (double)scale);

    float* wpd = wbp + layer * 1152;
    for (int k = 0; k < 11; ++k) wpd[k * 64 + c] = W[k * 64 + c] * scale;
    wpd[704 + c] = fmaf(B[c], scale, shift);
    unsigned* pw = (unsigned*)(wpd + 768);
    for (int kp = 0; kp < 6; ++kp) {
        float wlo = W[(2 * kp) * 64 + c] * scale;
        float whi = (2 * kp + 1 < 11) ? W[(2 * kp + 1) * 64 + c] * scale : 0.0f;
        pw[kp * 64 + c] = pk2(wlo, whi);
    }
}

__global__ void __launch_bounds__(256) gscanA_kernel(
    int* __restrict__ a, int* __restrict__ gbsum)
{
    int b = blockIdx.x, t = threadIdx.x;
    int i = b * 256 + t;
    int d = (i < GS_LEN) ? a[i] : 0;
    __shared__ int sh[256];
    sh[t] = d;
    __syncthreads();
    for (int off = 1; off < 256; off <<= 1) {
        int val = (t >= off) ? sh[t - off] : 0;
        __syncthreads();
        sh[t] += val;
        __syncthreads();
    }
    if (i < GS_LEN) a[i] = sh[t] - d;
    if (t == 255) gbsum[b] = sh[255];
}

__global__ void __launch_bounds__(256) gscanB_kernel(
    int* __restrict__ a, const int* __restrict__ gbsum)
{
    int b = blockIdx.x, t = threadIdx.x;
    __shared__ int sh[256];
    int s = 0;
    for (int j = t; j < b; j += 256) s += gbsum[j];
    sh[t] = s;
    __syncthreads();
    for (int off = 128; off > 0; off >>= 1) {
        if (t < off) sh[t] += sh[t + off];
        __syncthreads();
    }
    int boff = sh[0];
    int i = b * 256 + t;
    if (i < GS_LEN) a[i] += boff;
}

__global__ void __launch_bounds__(256) permB_kernel(
    const int* __restrict__ pr, const int* __restrict__ bhT,
    const int* __restrict__ rowptr, int4* __restrict__ perm4)
{
    int n = blockIdx.x * 256 + threadIdx.x;
    if (n >= NN) return;
    int p = pr[n];
    int bkt = p & 63, lrank = p >> 6, b = n >> 8;
    int pos = bhT[bkt * SCAN_BLOCKS + b] + lrank;
    perm4[pos] = make_int4(n, rowptr[n], rowptr[n + 1], 0);
}

// dot2 edge body: e-pairs straight from the fat record, packed f16 weights.
#define FAT_BODY2(LO, HI, XI)                                                \
    do {                                                                     \
        h2 ep0 = u2h((LO).x), ep1 = u2h((LO).y);                             \
        h2 ep2 = u2h((LO).z), ep3 = u2h((LO).w);                             \
        h2 ep4 = u2h((HI).x), ep5 = u2h((HI).y);                             \
        _Pragma("unroll")                                                    \
        for (int o = 0; o < 8; ++o) {                                        \
            float hh = breg[o];                                              \
            hh = FDOT2(ep0, pw[0][o], hh);                                   \
            hh = FDOT2(ep1, pw[1][o], hh);                                   \
            hh = FDOT2(ep2, pw[2][o], hh);                                   \
            hh = FDOT2(ep3, pw[3][o], hh);                                   \
            hh = FDOT2(ep4, pw[4][o], hh);                                   \
            hh = FDOT2(ep5, pw[5][o], hh);                                   \
            msg[o] = fmaf((XI), fast_tanh(hh), msg[o]);                      \
        }                                                                    \
    } while (0)

// Per-layer fused gather-message + mean + root + lrelu (+residual).
// waves_per_eu(2,4): allow up to 256 VGPR so the 48 packed-weight regs +
// state stay RESIDENT (hipcc's default occupancy heuristic remats them
// into the loop -> 48 extra loads/edge/thread; VGPR_Count 52 in r13).
template<int LAYER>
__global__ void __launch_bounds__(256)
__attribute__((amdgpu_waves_per_eu(2, 4))) layer_fat_kernel(
    const float* __restrict__ vres,
    const float* __restrict__ x,
    const uint4* __restrict__ A16, const uint4* __restrict__ B16,
    const int4* __restrict__ perm4,
    const float* __restrict__ wb,   // layer base: W'f32[704], b'[64], pk[384]
    const float* __restrict__ rw, const float* __restrict__ rb,
    float* __restrict__ out)
{
    int g = blockIdx.x * 256 + threadIdx.x;
    int4 pm = perm4[g >> 3];
    int n = pm.x, rp0 = pm.y, rp1 = pm.z;
    int i = g & 7;

    h2 pw[6][8];
    const unsigned* pwg = (const unsigned*)(wb + 768);
#pragma unroll
    for (int kp = 0; kp < 6; ++kp) {
        uint4 pa = *(const uint4*)(pwg + kp * 64 + i * 8);
        uint4 pb = *(const uint4*)(pwg + kp * 64 + i * 8 + 4);
        pw[kp][0] = u2h(pa.x); pw[kp][1] = u2h(pa.y);
        pw[kp][2] = u2h(pa.z); pw[kp][3] = u2h(pa.w);
        pw[kp][4] = u2h(pb.x); pw[kp][5] = u2h(pb.y);
        pw[kp][6] = u2h(pb.z); pw[kp][7] = u2h(pb.w);
    }
    float breg[8];
    {
        float4 ba = *(const float4*)(wb + 704 + i * 8);
        float4 bb = *(const float4*)(wb + 704 + i * 8 + 4);
        breg[0] = ba.x; breg[1] = ba.y; breg[2] = ba.z; breg[3] = ba.w;
        breg[4] = bb.x; breg[5] = bb.y; breg[6] = bb.z; breg[7] = bb.w;
    }

    float4 vd0 = *(const float4*)(vres + (size_t)n * 8);
    float4 vd1 = *(const float4*)(vres + (size_t)n * 8 + 4);
    float vd[8] = {vd0.x, vd0.y, vd0.z, vd0.w, vd1.x, vd1.y, vd1.z, vd1.w};

    float msg[8];
#pragma unroll
    for (int o = 0; o < 8; ++o) msg[o] = 0.0f;

    int j = rp0;
    for (; j + 2 <= rp1; j += 2) {
        uint4 lo0 = A16[j],     hi0 = B16[j];
        uint4 lo1 = A16[j + 1], hi1 = B16[j + 1];
        float xi0 = x[(size_t)(int)hi0.z * 8 + i];
        float xi1 = x[(size_t)(int)hi1.z * 8 + i];
        FAT_BODY2(lo0, hi0, xi0);
        FAT_BODY2(lo1, hi1, xi1);
    }
    if (j < rp1) {
        uint4 lo0 = A16[j], hi0 = B16[j];
        float xi0 = x[(size_t)(int)hi0.z * 8 + i];
        FAT_BODY2(lo0, hi0, xi0);
    }

#pragma unroll
    for (int o = 0; o < 8; ++o) {
        float m = msg[o];
        m += __shfl_xor(m, 1);
        m += __shfl_xor(m, 2);
        m += __shfl_xor(m, 4);
        msg[o] = m;
    }
    float mo = msg[0];
#pragma unroll
    for (int o = 1; o < 8; ++o) if (i == o) mo = msg[o];

    float cf = (float)(rp1 - rp0);
    float invc = __builtin_amdgcn_rcpf(fmaxf(cf, 1.0f));

    float xn[8];
    if (LAYER == 0) {
#pragma unroll
        for (int q = 0; q < 8; ++q) xn[q] = vd[q];
    } else {
        float4 x0 = *(const float4*)(x + (size_t)n * 8);
        float4 x1 = *(const float4*)(x + (size_t)n * 8 + 4);
        xn[0] = x0.x; xn[1] = x0.y; xn[2] = x0.z; xn[3] = x0.w;
        xn[4] = x1.x; xn[5] = x1.y; xn[6] = x1.z; xn[7] = x1.w;
    }
    float a = fmaf(mo, invc, rb[i]);
#pragma unroll
    for (int k = 0; k < 8; ++k) a = fmaf(xn[k], rw[k * 8 + i], a);
    float y = (a > 0.0f) ? a : SLOPE * a;
    if (LAYER == 1) y += vres[(size_t)n * 8 + i];
    out[(size_t)n * 8 + i] = y;
}

extern "C" void kernel_launch(void* const* d_in, const int* in_sizes, int n_in,
                              void* d_out, int out_size, void* d_ws, size_t ws_size,
                              hipStream_t stream) {
    const float* v  = (const float*)d_in[0];
    const int* ei   = (const int*)d_in[1];
    const float* ea = (const float*)d_in[2];
    const float* en_w0  = (const float*)d_in[3];
    const float* en_b0  = (const float*)d_in[4];
    const float* en_g0  = (const float*)d_in[5];
    const float* en_be0 = (const float*)d_in[6];
    const float* rw0    = (const float*)d_in[7];
    const float* rb0    = (const float*)d_in[8];
    const float* en_w1  = (const float*)d_in[9];
    const float* en_b1  = (const float*)d_in[10];
    const float* en_g1  = (const float*)d_in[11];
    const float* en_be1 = (const float*)d_in[12];
    const float* rw1    = (const float*)d_in[13];
    const float* rb1    = (const float*)d_in[14];

    char* ws = (char*)d_ws;
    float* partials = (float*)(ws);                   // 315,392 B
    float* wbp      = (float*)(ws + 327680);          // 9,216 B
    int*   deg      = (int*)  (ws + 340992);          // 400,000 B
    int*   rowptr   = (int*)  (ws + 741376);          // 400,004 B
    int*   bsum     = (int*)  (ws + 1141760);         // 1,564 B
    int*   pr       = (int*)  (ws + 1145856);         // 400,000 B
    int4*  perm4    = (int4*) (ws + 1546240);         // 1,600,000 B
    int*   bhT      = (int*)  (ws + 3547136);         // 100,096 B
    int*   gbsum    = (int*)  (ws + 3647488);         // 392 B
    float* v1       = (float*)(ws + 3649536);         // 3,200,000 B
    uint4* A16      = (uint4*)(ws + 6850560);         // 25,600,000 B
    int*   rank     = (int*)  (ws + 6850560);         // 6.4 MB, overlays A16
    uint4* B16      = (uint4*)(ws + 32450560);        // 25,600,000 B
    unsigned long long* recs8 = (unsigned long long*)(ws + 58050560); // 12.8 MB
    float* vout     = (float*)d_out;

    (void)hipMemsetAsync(deg, 0, NN * sizeof(int), stream);

    deg_rank_kernel<<<(NE + 255) / 256, 256, 0, stream>>>(ei, deg, rank);
    scanA_kernel<<<SCAN_BLOCKS, 256, 0, stream>>>(deg, rowptr, bsum, pr, bhT);
    scanC_kernel<<<SCAN_BLOCKS, 256, 0, stream>>>(rowptr, bsum);
    gscanA_kernel<<<GS_BLOCKS, 256, 0, stream>>>(bhT, gbsum);
    gscanB_kernel<<<GS_BLOCKS, 256, 0, stream>>>(bhT, gbsum);
    permB_kernel<<<SCAN_BLOCKS, 256, 0, stream>>>(pr, bhT, rowptr, perm4);
    thin_scatter_kernel<<<(NE + 255) / 256, 256, 0, stream>>>(ei, ea, rowptr, rank, recs8);
    expand_stats_kernel<<<EXP_BLOCKS, 256, 0, stream>>>(v, recs8, A16, B16, partials);
    bn_finalize_kernel<<<1, 128, 0, stream>>>(partials, en_w0, en_b0, en_g0, en_be0,
                                              en_w1, en_b1, en_g1, en_be1, wbp);

    const int LB = (NN * 8) / 256;   // 3125, exact
    layer_fat_kernel<0><<<LB, 256, 0, stream>>>(v, v,  A16, B16, perm4, wbp,        rw0, rb0, v1);
    layer_fat_kernel<1><<<LB, 256, 0, stream>>>(v, v1, A16, B16, perm4, wbp + 1152, rw1, rb1, vout);
}